// Round 9
// baseline (223.696 us; speedup 1.0000x reference)
//
#include <hip/hip_runtime.h>
#include <hip/hip_bf16.h>
#include <math.h>

#define N_PTS 1024
#define BT    128
typedef unsigned int u32;
typedef __attribute__((ext_vector_type(8))) short short8_t;   // 8 bf16 (4 VGPRs)
typedef __attribute__((ext_vector_type(4))) float f32x4;      // MFMA acc

__device__ __forceinline__ float bfi(u32 bits16) {
    union { u32 u; float f; } v; v.u = bits16 << 16; return v.f;
}
__device__ __forceinline__ unsigned short f2bf(float f) {     // RNE f32->bf16
    union { float f; u32 u; } v; v.f = f;
    return (unsigned short)((v.u + 0x7FFFu + ((v.u >> 16) & 1u)) >> 16);
}
__device__ __forceinline__ float ldf(const void* p, int i, bool bf) {
    return bf ? bfi(((const unsigned short*)p)[i]) : ((const float*)p)[i];
}
__device__ __forceinline__ float2 ldp(const void* pbase, int j, bool bf) {
    if (bf) {
        u32 w = ((const u32*)pbase)[j];
        return make_float2(bfi(w & 0xFFFFu), bfi(w >> 16));
    }
    return ((const float2*)pbase)[j];
}
__device__ __forceinline__ bool detect_bf16(const void* pts, int tid, int* s_flag) {
    if (tid < 64) {
        u32 w = ((const u32*)pts)[tid];
        float v = bfi(w & 0xFFFFu);
        bool ok = (v >= 0.0f) && (v <= 1.0f);
        unsigned long long m = __ballot(ok);
        if (tid == 0) *s_flag = (m == 0xFFFFFFFFFFFFFFFFull) ? 1 : 0;
    }
    __syncthreads();
    return *s_flag != 0;
}
__device__ __forceinline__ bool is_nb(float px, float py, float qx, float qy) {
    float dx = px - qx, dy = py - qy;
    // ref: sqrt_rn(rn(rn(dx*dx)+rn(dy*dy))) < 0.3f  <=>  d2 < 0.09f (ulp-exact)
    float d2 = __fadd_rn(__fmul_rn(dx, dx), __fmul_rn(dy, dy));
    return d2 < 0.09f;
}
__device__ __forceinline__ const void* pts_base(const void* pts, int bt, bool bf) {
    return bf ? (const void*)((const unsigned short*)pts + (size_t)bt * N_PTS * 2)
              : (const void*)((const float*)pts + (size_t)bt * N_PTS * 2);
}
// async global->LDS, 16B per lane (lands at lds_base + lane*16) [m97 pattern]
__device__ __forceinline__ void gload16(const u32* g, u32* l) {
    __builtin_amdgcn_global_load_lds((const __attribute__((address_space(1))) u32*)g,
                                     (__attribute__((address_space(3))) u32*)l, 16, 0, 0);
}
// wave-uniform broadcast of lane `i` (compile-time) via v_readlane (VALU, not DS pipe)
__device__ __forceinline__ float rdlane(float v, int i) {
    return __int_as_float(__builtin_amdgcn_readlane(__float_as_int(v), i));
}
// fast activations via v_exp_f32 (err ~1e-6, well under absmax budget)
__device__ __forceinline__ float sigm_f(float x) {
    return __fdividef(1.0f, 1.0f + __expf(-x));
}
__device__ __forceinline__ float tanh_f(float x) {
    float e = __expf(2.0f * x);                 // +inf / 0 limits give +-1 exactly
    return 1.0f - __fdividef(2.0f, e + 1.0f);
}
// build nibble->4xbf16 LUT (16 entries x 8B). Entry n dwords:
// d0 = bf(n&1) | bf(n&2)<<16, d1 = bf(n&4) | bf(n&8)<<16. Values 0x3F80/0 ==
// bit-identical to the old per-element expand -> MFMA inputs unchanged.
__device__ __forceinline__ void build_lut(u32* slut, int tid) {
    if (tid < 16) {
        u32 d0 = ((tid & 1) ? 0x3F80u : 0u) | (((tid & 2) ? 0x3F80u : 0u) << 16);
        u32 d1 = ((tid & 4) ? 0x3F80u : 0u) | (((tid & 8) ? 0x3F80u : 0u) << 16);
        slut[2 * tid] = d0;
        slut[2 * tid + 1] = d1;
    }
}
// byte -> short8 bf16 frag via two conflict-free ds_read_b64 (16 distinct 8B
// entries hit 16 distinct bank pairs; equal nibbles broadcast).
__device__ __forceinline__ short8_t expand8(const uint2* lut2, u32 by) {
    uint2 lo = lut2[by & 15u], hi = lut2[by >> 4];
    union { uint4 u4; short8_t s8; } cv;
    cv.u4 = make_uint4(lo.x, lo.y, hi.x, hi.y);
    return cv.s8;
}

// K1: pair sweep -> adjacency bitmask bm[bt][chunk(32)][row(1024)] + cnt->dinv. Zeros gsum.
__global__ __launch_bounds__(256) void k1_bm(const void* __restrict__ pts,
                                             float* __restrict__ dinv,
                                             float* __restrict__ gsum,
                                             u32* __restrict__ bm) {
    int blk = blockIdx.x, tid = threadIdx.x;
    int bt = blk >> 2, q = blk & 3;
    __shared__ float2 sp[N_PTS];
    __shared__ int s_flag;
    bool bf = detect_bf16(pts, tid, &s_flag);
    const void* pb = pts_base(pts, bt, bf);
    for (int j = tid; j < N_PTS; j += 256) sp[j] = ldp(pb, j, bf);
    if (blk < 32) gsum[blk * 256 + tid] = 0.0f;
    __syncthreads();
    int i = q * 256 + tid;
    float px = sp[i].x, py = sp[i].y;
    const float4* sp4 = (const float4*)sp;
    u32* bmrow = bm + (size_t)bt * 32768 + i;
    int cnt = 0;
    for (int c = 0; c < 32; c++) {
        u32 m = 0;
#pragma unroll
        for (int h = 0; h < 8; h++) {
            float4 s01 = sp4[c * 16 + 2 * h], s23 = sp4[c * 16 + 2 * h + 1];
            if (is_nb(px, py, s01.x, s01.y)) m |= 1u << (4 * h);
            if (is_nb(px, py, s01.z, s01.w)) m |= 1u << (4 * h + 1);
            if (is_nb(px, py, s23.x, s23.y)) m |= 1u << (4 * h + 2);
            if (is_nb(px, py, s23.z, s23.w)) m |= 1u << (4 * h + 3);
        }
        bmrow[c * 1024] = m;
        cnt += __popc(m);
    }
    dinv[bt * N_PTS + i] = 1.0f / sqrtf((float)cnt);
}

// K2 v4: agg0 via MFMA (u hi/lo bf16) with nibble-LUT expand. phase B unchanged.
__global__ __launch_bounds__(256) void k2_x1v(const void* __restrict__ pts,
                                              const void* __restrict__ W1,
                                              const void* __restrict__ b1,
                                              const float* __restrict__ dinv,
                                              const u32* __restrict__ bm,
                                              u32* __restrict__ x1vB) {
    int blk = blockIdx.x, tid = threadIdx.x;
    int bt = blk >> 2, q = blk & 3;
    __shared__ u32 sbm[8192];                    // 32 chunks x 256 rows
    __shared__ unsigned short u_lds[4][1032];    // {xh,yh,xl,yl} x 1024 (+pad)
    __shared__ float2 sax[256];
    __shared__ float  sdl[256];
    __shared__ u32 slut[32];
    __shared__ int s_flag;
    bool bf = detect_bf16(pts, tid, &s_flag);
    build_lut(slut, tid);
    const void* pb = pts_base(pts, bt, bf);
    for (int j = tid; j < N_PTS; j += 256) {
        float2 p = ldp(pb, j, bf);
        float d = dinv[bt * N_PTS + j];
        float ux = d * p.x, uy = d * p.y;
        unsigned short hx = f2bf(ux), hy = f2bf(uy);
        u_lds[0][j] = hx;
        u_lds[1][j] = hy;
        u_lds[2][j] = f2bf(ux - bfi(hx));
        u_lds[3][j] = f2bf(uy - bfi(hy));
    }
    const u32* bg_ = bm + (size_t)bt * 32768 + q * 256;
    for (int idx = tid; idx < 8192; idx += 256) {
        int c = idx >> 8, r = idx & 255;
        sbm[idx] = bg_[c * 1024 + r];
    }
    sdl[tid] = dinv[bt * N_PTS + q * 256 + tid];
    __syncthreads();

    int lane = tid & 63, w = tid >> 6;
    int l15 = lane & 15, quad = lane >> 4;
    f32x4 acc[4];   // [rf] : D rows = graph rows rf*16+quad*4+reg, col l15 = comp
#pragma unroll
    for (int rf = 0; rf < 4; rf++)
#pragma unroll
        for (int r = 0; r < 4; r++) acc[rf][r] = 0.0f;

    const unsigned short* urow = &u_lds[l15 & 3][0];
    const uint2* lut2 = (const uint2*)slut;
    for (int c = 0; c < 32; c++) {
        short8_t bu = *(const short8_t*)(urow + c * 32 + quad * 8);
#pragma unroll
        for (int rf = 0; rf < 4; rf++) {
            u32 mw = sbm[c * 256 + w * 64 + rf * 16 + l15];
            u32 by = (mw >> (quad * 8)) & 0xFFu;
            acc[rf] = __builtin_amdgcn_mfma_f32_16x16x32_bf16(expand8(lut2, by), bu, acc[rf], 0, 0, 0);
        }
    }
    // combine hi+lo (l15: 0 gets 2's acc = x_lo, 1 gets 3's = y_lo); scale by di
#pragma unroll
    for (int rf = 0; rf < 4; rf++) {
#pragma unroll
        for (int r = 0; r < 4; r++) {
            float vsum = acc[rf][r] + __shfl_xor(acc[rf][r], 2, 64);
            int row = w * 64 + rf * 16 + quad * 4 + r;
            float sc = vsum * sdl[row];
            if (l15 == 0)      sax[row].x = sc;
            else if (l15 == 1) sax[row].y = sc;
        }
    }
    __syncthreads();
    // phase B: tiles q*4..q*4+4; thread = (ch, wave=jj-quarter)  [unchanged]
    int ch = tid & 63, wq = tid >> 6;
    float w0 = ldf(W1, 2 * ch, bf), w1v = ldf(W1, 2 * ch + 1, bf), bb = ldf(b1, ch, bf);
    for (int tt = 0; tt < 4; tt++) {
        u32 ow[8];
#pragma unroll
        for (int k2i = 0; k2i < 8; k2i++) {
            int lj = tt * 64 + wq * 16 + 2 * k2i;
            float2 a0 = sax[lj], a1 = sax[lj + 1];
            float v0 = sdl[lj]     * fmaxf(fmaf(w0, a0.x, fmaf(w1v, a0.y, bb)), 0.0f);
            float v1 = sdl[lj + 1] * fmaxf(fmaf(w0, a1.x, fmaf(w1v, a1.y, bb)), 0.0f);
            ow[k2i] = (u32)f2bf(v0) | ((u32)f2bf(v1) << 16);
        }
        u32* dst = x1vB + ((size_t)(bt * 16 + q * 4 + tt) * 64 + ch) * 36 + wq * 8;
        *(uint4*)dst = make_uint4(ow[0], ow[1], ow[2], ow[3]);
        *(uint4*)(dst + 4) = make_uint4(ow[4], ow[5], ow[6], ow[7]);
    }
}

// K3: D^T = x1v^T @ A with nibble-LUT expand; dbuf gload16; W2 epilogue.
__global__ __launch_bounds__(256) void k3_mfma(const void* __restrict__ pts,
                                               const void* __restrict__ W2,
                                               const void* __restrict__ b2,
                                               const float* __restrict__ dinv,
                                               const u32* __restrict__ bm,
                                               const u32* __restrict__ x1vB,
                                               float* __restrict__ gsum) {
    // pool dwords: sbm[0,8192) xf0[8192,10496) xf1[10496,12800) W2B[12800,15104)
    // sdi[15104,15360) sb2[15360,15424). dump overlays [0,9216) post-K-loop.
    __shared__ u32 pool[15424];
    __shared__ u32 slut[32];
    __shared__ int s_flag;
    float* poolf = (float*)pool;
    int tid = threadIdx.x, lane = tid & 63, w = tid >> 6;
    int l15 = lane & 15, quad = lane >> 4;
    int blk = blockIdx.x, bt = blk & 127, rowblk = blk >> 7;
    bool bf = detect_bf16(pts, tid, &s_flag);
    build_lut(slut, tid);

    const u32* xg = x1vB + (size_t)bt * 36864;   // 16 tiles * 2304 dw
    for (int it = w; it < 9; it += 4)            // prefetch tile 0 -> xf0
        gload16(xg + it * 256 + lane * 4, pool + 8192 + it * 256 + lane * 4);

    const u32* bg_ = bm + (size_t)bt * 32768 + rowblk * 256;
    for (int idx = tid; idx < 8192; idx += 256) {
        int c = idx >> 8, r = idx & 255;
        pool[idx] = bg_[c * 1024 + r];
    }
    unsigned short* W2B = (unsigned short*)(pool + 12800);
    for (int idx = tid; idx < 4096; idx += 256) {
        int o = idx >> 6, c = idx & 63;
        W2B[o * 72 + c] = f2bf(ldf(W2, idx, bf));
    }
    if (tid < 256) poolf[15104 + tid] = dinv[bt * N_PTS + rowblk * 256 + tid];
    if (tid < 64)  poolf[15360 + tid] = ldf(b2, tid, bf);

    f32x4 acc[4][4];   // [rf(row16-block)][nb(ch16-block)]
#pragma unroll
    for (int rf = 0; rf < 4; rf++)
#pragma unroll
        for (int nb = 0; nb < 4; nb++)
#pragma unroll
            for (int r = 0; r < 4; r++) acc[rf][nb][r] = 0.0f;

    const uint2* lut2 = (const uint2*)slut;
    for (int t = 0; t < 16; t++) {
        __syncthreads();   // drains vmcnt -> current buf ready
        if (t + 1 < 16) {
            u32* dst = pool + ((t & 1) ? 8192 : 10496);
            const u32* src = xg + (t + 1) * 2304;
            for (int it = w; it < 9; it += 4)
                gload16(src + it * 256 + lane * 4, dst + it * 256 + lane * 4);
        }
        const unsigned short* xf = (const unsigned short*)(pool + ((t & 1) ? 10496 : 8192));
#pragma unroll
        for (int ks = 0; ks < 2; ks++) {
            short8_t bq[4];
#pragma unroll
            for (int rf = 0; rf < 4; rf++) {
                u32 mw = pool[(2 * t + ks) * 256 + w * 64 + rf * 16 + l15];
                u32 by = (mw >> (quad * 8)) & 0xFFu;
                bq[rf] = expand8(lut2, by);
            }
#pragma unroll
            for (int nb = 0; nb < 4; nb++) {
                short8_t af = *(const short8_t*)(xf + (nb * 16 + l15) * 72 + ks * 32 + quad * 8);
#pragma unroll
                for (int rf = 0; rf < 4; rf++)
                    acc[rf][nb] = __builtin_amdgcn_mfma_f32_16x16x32_bf16(af, bq[rf], acc[rf][nb], 0, 0, 0);
            }
        }
    }
    __syncthreads();

    // dump di*D^T as bf16 [256 rows][72 shorts] (pad rows, 2-way-free banks)
    u32* dump = pool;
#pragma unroll
    for (int rf = 0; rf < 4; rf++) {
        int rn = w * 64 + rf * 16 + l15;
        float di = poolf[15104 + rn];
#pragma unroll
        for (int nb = 0; nb < 4; nb++) {
            u32 lo = (u32)f2bf(acc[rf][nb][0] * di) | ((u32)f2bf(acc[rf][nb][1] * di) << 16);
            u32 hi = (u32)f2bf(acc[rf][nb][2] * di) | ((u32)f2bf(acc[rf][nb][3] * di) << 16);
            u32* dst = dump + rn * 36 + nb * 8 + quad * 2;
            dst[0] = lo; dst[1] = hi;
        }
    }
    __syncthreads();
    f32x4 xacc[4][4];  // [ob(o16-block)][rf]
#pragma unroll
    for (int ob = 0; ob < 4; ob++)
#pragma unroll
        for (int rf = 0; rf < 4; rf++)
#pragma unroll
            for (int r = 0; r < 4; r++) xacc[ob][rf][r] = 0.0f;
#pragma unroll
    for (int ks2 = 0; ks2 < 2; ks2++) {
        short8_t b2f[4];
#pragma unroll
        for (int rf = 0; rf < 4; rf++)
            b2f[rf] = *(const short8_t*)((const unsigned short*)dump +
                        (w * 64 + rf * 16 + l15) * 72 + ks2 * 32 + quad * 8);
#pragma unroll
        for (int ob = 0; ob < 4; ob++) {
            short8_t a2 = *(const short8_t*)(W2B + (ob * 16 + l15) * 72 + ks2 * 32 + quad * 8);
#pragma unroll
            for (int rf = 0; rf < 4; rf++)
                xacc[ob][rf] = __builtin_amdgcn_mfma_f32_16x16x32_bf16(a2, b2f[rf], xacc[ob][rf], 0, 0, 0);
        }
    }
#pragma unroll
    for (int ob = 0; ob < 4; ob++) {
#pragma unroll
        for (int r = 0; r < 4; r++) {
            int o = ob * 16 + quad * 4 + r;
            float bb = poolf[15360 + o];
            float s = 0.0f;
#pragma unroll
            for (int rf = 0; rf < 4; rf++) s += fmaxf(xacc[ob][rf][r] + bb, 0.0f);
            s += __shfl_down(s, 8, 16);
            s += __shfl_down(s, 4, 16);
            s += __shfl_down(s, 2, 16);
            s += __shfl_down(s, 1, 16);
            if (l15 == 0) atomicAdd(&gsum[bt * 64 + o], s);
        }
    }
}

// K4a: per-(b,t) precompute (parallel, 128 blocks x 384 thr, 1 blk/CU).
// x[t] = bg + Wg@gm  then  gi[t][r] = bih[r] + Wih[r,:]@x.
__global__ __launch_bounds__(384, 1) void k4a_gi(const void* __restrict__ pts,
                                                 const void* __restrict__ Wg,
                                                 const void* __restrict__ bg,
                                                 const void* __restrict__ Wih,
                                                 const void* __restrict__ bih,
                                                 const float* __restrict__ gsum,
                                                 float* __restrict__ gi_ws) {
    int blk = blockIdx.x, tid = threadIdx.x;   // blk = b*32 + t
    __shared__ float s_gm[64];
    __shared__ float s_x[64];
    __shared__ int s_flag;
    bool bf = detect_bf16(pts, tid, &s_flag);
    if (tid < 64) s_gm[tid] = gsum[(size_t)blk * 64 + tid] * (1.0f / 1024.0f);
    int r = tid;
    float wv[64];
    if (bf) {
#pragma unroll
        for (int k = 0; k < 64; k++) wv[k] = bfi(((const unsigned short*)Wih)[r * 64 + k]);
    } else {
        const float4* wr = (const float4*)Wih + r * 16;
#pragma unroll
        for (int qq = 0; qq < 16; qq++) {
            float4 v = wr[qq];
            wv[4*qq] = v.x; wv[4*qq+1] = v.y; wv[4*qq+2] = v.z; wv[4*qq+3] = v.w;
        }
    }
    float br = ldf(bih, r, bf);
    float wg[64];
    if (tid < 64) {                            // wave 0: Wg row c = tid
        if (bf) {
#pragma unroll
            for (int k = 0; k < 64; k++) wg[k] = bfi(((const unsigned short*)Wg)[tid * 64 + k]);
        } else {
            const float4* wr = (const float4*)Wg + tid * 16;
#pragma unroll
            for (int qq = 0; qq < 16; qq++) {
                float4 v = wr[qq];
                wg[4*qq] = v.x; wg[4*qq+1] = v.y; wg[4*qq+2] = v.z; wg[4*qq+3] = v.w;
            }
        }
    }
    __syncthreads();                           // s_gm ready
    if (tid < 64) {
        float gmv = s_gm[tid];                 // lane c holds gm[c]
        float s0 = ldf(bg, tid, bf), s1 = 0.f, s2 = 0.f, s3 = 0.f;
#pragma unroll
        for (int k = 0; k < 64; k += 4) {
            s0 = fmaf(wg[k],     rdlane(gmv, k),     s0);
            s1 = fmaf(wg[k + 1], rdlane(gmv, k + 1), s1);
            s2 = fmaf(wg[k + 2], rdlane(gmv, k + 2), s2);
            s3 = fmaf(wg[k + 3], rdlane(gmv, k + 3), s3);
        }
        s_x[tid] = (s0 + s1) + (s2 + s3);
    }
    __syncthreads();                           // s_x ready
    float xv = s_x[tid & 63];                  // lane k holds x[k]
    float s0 = br, s1 = 0.f, s2 = 0.f, s3 = 0.f;
#pragma unroll
    for (int k = 0; k < 64; k += 4) {
        s0 = fmaf(wv[k],     rdlane(xv, k),     s0);
        s1 = fmaf(wv[k + 1], rdlane(xv, k + 1), s1);
        s2 = fmaf(wv[k + 2], rdlane(xv, k + 2), s2);
        s3 = fmaf(wv[k + 3], rdlane(xv, k + 3), s3);
    }
    gi_ws[(size_t)blk * 384 + r] = (s0 + s1) + (s2 + s3);
}

// K4b v5: scan only. R8 post-mortem found VGPR_Count=68 => compiler was
// REMATERIALIZING the Whh "register" weights from L2 inside every scan step
// (~16 dwordx4 x 200cy injected per step; 41us vs ~15us floor). Fix: load the
// half-row through a VOLATILE pointer into a statically-indexed float4[16] —
// volatile loads can't be re-executed/eliminated, forcing VGPR residency
// (~140 < 168 cap at 3 waves/SIMD). FMA order identical (s0..s3, k=4q+i) ->
// bit-identical scan.
__global__ __launch_bounds__(768, 1) void k4b_scan(const void* __restrict__ pts,
                                                   const void* __restrict__ Whh,
                                                   const void* __restrict__ bhh,
                                                   const void* __restrict__ Wf,
                                                   const void* __restrict__ bf_,
                                                   const float* __restrict__ gi_ws,
                                                   float* __restrict__ out) {
    int b = blockIdx.x, tid = threadIdx.x;
    __shared__ float s_gi[12288];      // 48 KB: [t][384]
    __shared__ float s_part[2][768];   // 6 KB, double-buffered partial dots
    __shared__ float s_hm[128];
    __shared__ int s_flag;
    bool bf = detect_bf16(pts, tid, &s_flag);
    const u32* gi_g = (const u32*)gi_ws + (size_t)b * 12288;
    u32* s_gi_u = (u32*)s_gi;
#pragma unroll
    for (int j = 0; j < 4; j++)
        gload16(gi_g + j * 3072 + tid * 4, s_gi_u + j * 3072 + tid * 4);

    int hi = (tid >= 384) ? 1 : 0;      // wave-uniform (384 = 6 waves)
    int r = tid - hi * 384;
    int lane = tid & 63;
    // Whh half-row -> float4[16], loaded VOLATILE (pinned in VGPRs)
    float4 wh4[16];
    {
        int koff = hi * 64;
        if (bf) {
            const volatile uint2* wr =
                (const volatile uint2*)((const unsigned short*)Whh + r * 128 + koff);
#pragma unroll
            for (int qq = 0; qq < 16; qq++) {
                u32 a = wr[qq].x, bwd = wr[qq].y;   // volatile reads
                wh4[qq] = make_float4(bfi(a & 0xFFFFu), bfi(a >> 16),
                                      bfi(bwd & 0xFFFFu), bfi(bwd >> 16));
            }
        } else {
            const volatile float4* wr = (const volatile float4*)Whh + (r * 128 + koff) / 4;
#pragma unroll
            for (int qq = 0; qq < 16; qq++) {
                float4 v;
                v.x = wr[qq].x; v.y = wr[qq].y; v.z = wr[qq].z; v.w = wr[qq].w;
                wh4[qq] = v;
            }
        }
    }
    float bhr = hi ? 0.0f : ldf(bhh, r, bf);
    int c = hi * 64 + lane;             // the h index this thread owns/broadcasts
    float hval = 0.0f;
    float hsum = 0.0f;
    __syncthreads();                    // drains vmcnt -> s_gi ready

    for (int t = 0; t < 32; t++) {
        float gi_r = s_gi[t * 384 + c];
        float gi_z = s_gi[t * 384 + 128 + c];
        float gi_n = s_gi[t * 384 + 256 + c];
        float s0 = bhr, s1 = 0.f, s2 = 0.f, s3 = 0.f;
#pragma unroll
        for (int q = 0; q < 16; q++) {   // k = 4q+i: same FMA order as wh2[k]
            float4 wv4 = wh4[q];
            s0 = fmaf(wv4.x, rdlane(hval, 4 * q),     s0);
            s1 = fmaf(wv4.y, rdlane(hval, 4 * q + 1), s1);
            s2 = fmaf(wv4.z, rdlane(hval, 4 * q + 2), s2);
            s3 = fmaf(wv4.w, rdlane(hval, 4 * q + 3), s3);
        }
        s_part[t & 1][tid] = (s0 + s1) + (s2 + s3);
        __syncthreads();                // the ONLY barrier per step
        const float* P = s_part[t & 1];
        float gr = gi_r + P[c]       + P[384 + c];
        float gz = gi_z + P[128 + c] + P[512 + c];
        float hn =        P[256 + c] + P[640 + c];
        float rr = sigm_f(gr);
        float z  = sigm_f(gz);
        float n  = tanh_f(fmaf(rr, hn, gi_n));
        hval = fmaf(z, hval - n, n);    // (1-z)*n + z*h
        hsum += hval;
    }
    if (tid < 64) s_hm[tid] = hsum * (1.0f / 32.0f);
    else if (tid >= 384 && tid < 448) s_hm[64 + lane] = hsum * (1.0f / 32.0f);
    __syncthreads();
    if (tid < 128) {
        float hm = s_hm[tid];
        s_part[0][tid]       = ldf(Wf, tid, bf) * hm;
        s_part[0][128 + tid] = ldf(Wf, 128 + tid, bf) * hm;
    }
    __syncthreads();
    if (tid < 2) {
        float s = ldf(bf_, tid, bf);
        for (int k = 0; k < 128; k++) s += s_part[0][tid * 128 + k];
        out[b * 2 + tid] = s;   // f32 output (verified R4)
    }
}

extern "C" void kernel_launch(void* const* d_in, const int* in_sizes, int n_in,
                              void* d_out, int out_size, void* d_ws, size_t ws_size,
                              hipStream_t stream) {
    const void* pts = d_in[0];
    const void* W1  = d_in[1];
    const void* b1  = d_in[2];
    const void* W2  = d_in[3];
    const void* b2  = d_in[4];
    const void* Wg  = d_in[5];
    const void* bg  = d_in[6];
    const void* Wih = d_in[7];
    const void* Whh = d_in[8];
    const void* bih = d_in[9];
    const void* bhh = d_in[10];
    const void* Wf  = d_in[11];
    const void* bf_ = d_in[12];

    // ws: dinv 512K | gsum 32K | bm 16M | x1vB 18M  (~34.5 MB)
    float* dinv = (float*)d_ws;
    float* gsum = dinv + (size_t)BT * N_PTS;
    u32*   bm   = (u32*)(gsum + BT * 64);
    u32*   x1vB = bm + (size_t)BT * 32768;
    // gi (B*T*384 f32 = 192 KB) reuses x1vB region — x1vB is dead after k3
    // (stream-serial), and k2 rewrites it fresh every iteration.
    float* gi_ws = (float*)x1vB;

    k1_bm  <<<512, 256, 0, stream>>>(pts, dinv, gsum, bm);
    k2_x1v <<<512, 256, 0, stream>>>(pts, W1, b1, dinv, bm, x1vB);
    k3_mfma<<<512, 256, 0, stream>>>(pts, W2, b2, dinv, bm, x1vB, gsum);
    k4a_gi <<<128, 384, 0, stream>>>(pts, Wg, bg, Wih, bih, gsum, gi_ws);
    k4b_scan<<<4, 768, 0, stream>>>(pts, Whh, bhh, Wf, bf_, gi_ws, (float*)d_out);
}

// Round 11
// 205.291 us; speedup vs baseline: 1.0897x; 1.0897x over previous
//
#include <hip/hip_runtime.h>
#include <hip/hip_bf16.h>
#include <math.h>

#define N_PTS 1024
#define BT    128
typedef unsigned int u32;
typedef __attribute__((ext_vector_type(8))) short short8_t;   // 8 bf16 (4 VGPRs)
typedef __attribute__((ext_vector_type(4))) float f32x4;      // MFMA acc

__device__ __forceinline__ float bfi(u32 bits16) {
    union { u32 u; float f; } v; v.u = bits16 << 16; return v.f;
}
__device__ __forceinline__ unsigned short f2bf(float f) {     // RNE f32->bf16
    union { float f; u32 u; } v; v.f = f;
    return (unsigned short)((v.u + 0x7FFFu + ((v.u >> 16) & 1u)) >> 16);
}
__device__ __forceinline__ float ldf(const void* p, int i, bool bf) {
    return bf ? bfi(((const unsigned short*)p)[i]) : ((const float*)p)[i];
}
__device__ __forceinline__ float2 ldp(const void* pbase, int j, bool bf) {
    if (bf) {
        u32 w = ((const u32*)pbase)[j];
        return make_float2(bfi(w & 0xFFFFu), bfi(w >> 16));
    }
    return ((const float2*)pbase)[j];
}
__device__ __forceinline__ bool detect_bf16(const void* pts, int tid, int* s_flag) {
    if (tid < 64) {
        u32 w = ((const u32*)pts)[tid];
        float v = bfi(w & 0xFFFFu);
        bool ok = (v >= 0.0f) && (v <= 1.0f);
        unsigned long long m = __ballot(ok);
        if (tid == 0) *s_flag = (m == 0xFFFFFFFFFFFFFFFFull) ? 1 : 0;
    }
    __syncthreads();
    return *s_flag != 0;
}
__device__ __forceinline__ bool is_nb(float px, float py, float qx, float qy) {
    float dx = px - qx, dy = py - qy;
    // ref: sqrt_rn(rn(rn(dx*dx)+rn(dy*dy))) < 0.3f  <=>  d2 < 0.09f (ulp-exact)
    float d2 = __fadd_rn(__fmul_rn(dx, dx), __fmul_rn(dy, dy));
    return d2 < 0.09f;
}
__device__ __forceinline__ const void* pts_base(const void* pts, int bt, bool bf) {
    return bf ? (const void*)((const unsigned short*)pts + (size_t)bt * N_PTS * 2)
              : (const void*)((const float*)pts + (size_t)bt * N_PTS * 2);
}
// async global->LDS, 16B per lane (lands at lds_base + lane*16) [m97 pattern]
__device__ __forceinline__ void gload16(const u32* g, u32* l) {
    __builtin_amdgcn_global_load_lds((const __attribute__((address_space(1))) u32*)g,
                                     (__attribute__((address_space(3))) u32*)l, 16, 0, 0);
}
// wave-uniform broadcast of lane `i` (compile-time) via v_readlane (VALU, not DS pipe)
__device__ __forceinline__ float rdlane(float v, int i) {
    return __int_as_float(__builtin_amdgcn_readlane(__float_as_int(v), i));
}
// fast activations via v_exp_f32 (err ~1e-6, well under absmax budget)
__device__ __forceinline__ float sigm_f(float x) {
    return __fdividef(1.0f, 1.0f + __expf(-x));
}
__device__ __forceinline__ float tanh_f(float x) {
    float e = __expf(2.0f * x);                 // +inf / 0 limits give +-1 exactly
    return 1.0f - __fdividef(2.0f, e + 1.0f);
}
// build nibble->4xbf16 LUT (16 entries x 8B). Entry n dwords:
// d0 = bf(n&1) | bf(n&2)<<16, d1 = bf(n&4) | bf(n&8)<<16. Values 0x3F80/0 ==
// bit-identical to the old per-element expand -> MFMA inputs unchanged.
__device__ __forceinline__ void build_lut(u32* slut, int tid) {
    if (tid < 16) {
        u32 d0 = ((tid & 1) ? 0x3F80u : 0u) | (((tid & 2) ? 0x3F80u : 0u) << 16);
        u32 d1 = ((tid & 4) ? 0x3F80u : 0u) | (((tid & 8) ? 0x3F80u : 0u) << 16);
        slut[2 * tid] = d0;
        slut[2 * tid + 1] = d1;
    }
}
// byte -> short8 bf16 frag via two conflict-free ds_read_b64 (16 distinct 8B
// entries hit 16 distinct bank pairs; equal nibbles broadcast).
__device__ __forceinline__ short8_t expand8(const uint2* lut2, u32 by) {
    uint2 lo = lut2[by & 15u], hi = lut2[by >> 4];
    union { uint4 u4; short8_t s8; } cv;
    cv.u4 = make_uint4(lo.x, lo.y, hi.x, hi.y);
    return cv.s8;
}

// K1: pair sweep -> adjacency bitmask bm[bt][chunk(32)][row(1024)] + cnt->dinv. Zeros gsum.
__global__ __launch_bounds__(256) void k1_bm(const void* __restrict__ pts,
                                             float* __restrict__ dinv,
                                             float* __restrict__ gsum,
                                             u32* __restrict__ bm) {
    int blk = blockIdx.x, tid = threadIdx.x;
    int bt = blk >> 2, q = blk & 3;
    __shared__ float2 sp[N_PTS];
    __shared__ int s_flag;
    bool bf = detect_bf16(pts, tid, &s_flag);
    const void* pb = pts_base(pts, bt, bf);
    for (int j = tid; j < N_PTS; j += 256) sp[j] = ldp(pb, j, bf);
    if (blk < 32) gsum[blk * 256 + tid] = 0.0f;
    __syncthreads();
    int i = q * 256 + tid;
    float px = sp[i].x, py = sp[i].y;
    const float4* sp4 = (const float4*)sp;
    u32* bmrow = bm + (size_t)bt * 32768 + i;
    int cnt = 0;
    for (int c = 0; c < 32; c++) {
        u32 m = 0;
#pragma unroll
        for (int h = 0; h < 8; h++) {
            float4 s01 = sp4[c * 16 + 2 * h], s23 = sp4[c * 16 + 2 * h + 1];
            if (is_nb(px, py, s01.x, s01.y)) m |= 1u << (4 * h);
            if (is_nb(px, py, s01.z, s01.w)) m |= 1u << (4 * h + 1);
            if (is_nb(px, py, s23.x, s23.y)) m |= 1u << (4 * h + 2);
            if (is_nb(px, py, s23.z, s23.w)) m |= 1u << (4 * h + 3);
        }
        bmrow[c * 1024] = m;
        cnt += __popc(m);
    }
    dinv[bt * N_PTS + i] = 1.0f / sqrtf((float)cnt);
}

// K2 v4: agg0 via MFMA (u hi/lo bf16) with nibble-LUT expand. phase B unchanged.
__global__ __launch_bounds__(256) void k2_x1v(const void* __restrict__ pts,
                                              const void* __restrict__ W1,
                                              const void* __restrict__ b1,
                                              const float* __restrict__ dinv,
                                              const u32* __restrict__ bm,
                                              u32* __restrict__ x1vB) {
    int blk = blockIdx.x, tid = threadIdx.x;
    int bt = blk >> 2, q = blk & 3;
    __shared__ u32 sbm[8192];                    // 32 chunks x 256 rows
    __shared__ unsigned short u_lds[4][1032];    // {xh,yh,xl,yl} x 1024 (+pad)
    __shared__ float2 sax[256];
    __shared__ float  sdl[256];
    __shared__ u32 slut[32];
    __shared__ int s_flag;
    bool bf = detect_bf16(pts, tid, &s_flag);
    build_lut(slut, tid);
    const void* pb = pts_base(pts, bt, bf);
    for (int j = tid; j < N_PTS; j += 256) {
        float2 p = ldp(pb, j, bf);
        float d = dinv[bt * N_PTS + j];
        float ux = d * p.x, uy = d * p.y;
        unsigned short hx = f2bf(ux), hy = f2bf(uy);
        u_lds[0][j] = hx;
        u_lds[1][j] = hy;
        u_lds[2][j] = f2bf(ux - bfi(hx));
        u_lds[3][j] = f2bf(uy - bfi(hy));
    }
    const u32* bg_ = bm + (size_t)bt * 32768 + q * 256;
    for (int idx = tid; idx < 8192; idx += 256) {
        int c = idx >> 8, r = idx & 255;
        sbm[idx] = bg_[c * 1024 + r];
    }
    sdl[tid] = dinv[bt * N_PTS + q * 256 + tid];
    __syncthreads();

    int lane = tid & 63, w = tid >> 6;
    int l15 = lane & 15, quad = lane >> 4;
    f32x4 acc[4];   // [rf] : D rows = graph rows rf*16+quad*4+reg, col l15 = comp
#pragma unroll
    for (int rf = 0; rf < 4; rf++)
#pragma unroll
        for (int r = 0; r < 4; r++) acc[rf][r] = 0.0f;

    const unsigned short* urow = &u_lds[l15 & 3][0];
    const uint2* lut2 = (const uint2*)slut;
    for (int c = 0; c < 32; c++) {
        short8_t bu = *(const short8_t*)(urow + c * 32 + quad * 8);
#pragma unroll
        for (int rf = 0; rf < 4; rf++) {
            u32 mw = sbm[c * 256 + w * 64 + rf * 16 + l15];
            u32 by = (mw >> (quad * 8)) & 0xFFu;
            acc[rf] = __builtin_amdgcn_mfma_f32_16x16x32_bf16(expand8(lut2, by), bu, acc[rf], 0, 0, 0);
        }
    }
    // combine hi+lo (l15: 0 gets 2's acc = x_lo, 1 gets 3's = y_lo); scale by di
#pragma unroll
    for (int rf = 0; rf < 4; rf++) {
#pragma unroll
        for (int r = 0; r < 4; r++) {
            float vsum = acc[rf][r] + __shfl_xor(acc[rf][r], 2, 64);
            int row = w * 64 + rf * 16 + quad * 4 + r;
            float sc = vsum * sdl[row];
            if (l15 == 0)      sax[row].x = sc;
            else if (l15 == 1) sax[row].y = sc;
        }
    }
    __syncthreads();
    // phase B: tiles q*4..q*4+4; thread = (ch, wave=jj-quarter)  [unchanged]
    int ch = tid & 63, wq = tid >> 6;
    float w0 = ldf(W1, 2 * ch, bf), w1v = ldf(W1, 2 * ch + 1, bf), bb = ldf(b1, ch, bf);
    for (int tt = 0; tt < 4; tt++) {
        u32 ow[8];
#pragma unroll
        for (int k2i = 0; k2i < 8; k2i++) {
            int lj = tt * 64 + wq * 16 + 2 * k2i;
            float2 a0 = sax[lj], a1 = sax[lj + 1];
            float v0 = sdl[lj]     * fmaxf(fmaf(w0, a0.x, fmaf(w1v, a0.y, bb)), 0.0f);
            float v1 = sdl[lj + 1] * fmaxf(fmaf(w0, a1.x, fmaf(w1v, a1.y, bb)), 0.0f);
            ow[k2i] = (u32)f2bf(v0) | ((u32)f2bf(v1) << 16);
        }
        u32* dst = x1vB + ((size_t)(bt * 16 + q * 4 + tt) * 64 + ch) * 36 + wq * 8;
        *(uint4*)dst = make_uint4(ow[0], ow[1], ow[2], ow[3]);
        *(uint4*)(dst + 4) = make_uint4(ow[4], ow[5], ow[6], ow[7]);
    }
}

// K3: D^T = x1v^T @ A with nibble-LUT expand; dbuf gload16; W2 epilogue.
__global__ __launch_bounds__(256) void k3_mfma(const void* __restrict__ pts,
                                               const void* __restrict__ W2,
                                               const void* __restrict__ b2,
                                               const float* __restrict__ dinv,
                                               const u32* __restrict__ bm,
                                               const u32* __restrict__ x1vB,
                                               float* __restrict__ gsum) {
    // pool dwords: sbm[0,8192) xf0[8192,10496) xf1[10496,12800) W2B[12800,15104)
    // sdi[15104,15360) sb2[15360,15424). dump overlays [0,9216) post-K-loop.
    __shared__ u32 pool[15424];
    __shared__ u32 slut[32];
    __shared__ int s_flag;
    float* poolf = (float*)pool;
    int tid = threadIdx.x, lane = tid & 63, w = tid >> 6;
    int l15 = lane & 15, quad = lane >> 4;
    int blk = blockIdx.x, bt = blk & 127, rowblk = blk >> 7;
    bool bf = detect_bf16(pts, tid, &s_flag);
    build_lut(slut, tid);

    const u32* xg = x1vB + (size_t)bt * 36864;   // 16 tiles * 2304 dw
    for (int it = w; it < 9; it += 4)            // prefetch tile 0 -> xf0
        gload16(xg + it * 256 + lane * 4, pool + 8192 + it * 256 + lane * 4);

    const u32* bg_ = bm + (size_t)bt * 32768 + rowblk * 256;
    for (int idx = tid; idx < 8192; idx += 256) {
        int c = idx >> 8, r = idx & 255;
        pool[idx] = bg_[c * 1024 + r];
    }
    unsigned short* W2B = (unsigned short*)(pool + 12800);
    for (int idx = tid; idx < 4096; idx += 256) {
        int o = idx >> 6, c = idx & 63;
        W2B[o * 72 + c] = f2bf(ldf(W2, idx, bf));
    }
    if (tid < 256) poolf[15104 + tid] = dinv[bt * N_PTS + rowblk * 256 + tid];
    if (tid < 64)  poolf[15360 + tid] = ldf(b2, tid, bf);

    f32x4 acc[4][4];   // [rf(row16-block)][nb(ch16-block)]
#pragma unroll
    for (int rf = 0; rf < 4; rf++)
#pragma unroll
        for (int nb = 0; nb < 4; nb++)
#pragma unroll
            for (int r = 0; r < 4; r++) acc[rf][nb][r] = 0.0f;

    const uint2* lut2 = (const uint2*)slut;
    for (int t = 0; t < 16; t++) {
        __syncthreads();   // drains vmcnt -> current buf ready
        if (t + 1 < 16) {
            u32* dst = pool + ((t & 1) ? 8192 : 10496);
            const u32* src = xg + (t + 1) * 2304;
            for (int it = w; it < 9; it += 4)
                gload16(src + it * 256 + lane * 4, dst + it * 256 + lane * 4);
        }
        const unsigned short* xf = (const unsigned short*)(pool + ((t & 1) ? 10496 : 8192));
#pragma unroll
        for (int ks = 0; ks < 2; ks++) {
            short8_t bq[4];
#pragma unroll
            for (int rf = 0; rf < 4; rf++) {
                u32 mw = pool[(2 * t + ks) * 256 + w * 64 + rf * 16 + l15];
                u32 by = (mw >> (quad * 8)) & 0xFFu;
                bq[rf] = expand8(lut2, by);
            }
#pragma unroll
            for (int nb = 0; nb < 4; nb++) {
                short8_t af = *(const short8_t*)(xf + (nb * 16 + l15) * 72 + ks * 32 + quad * 8);
#pragma unroll
                for (int rf = 0; rf < 4; rf++)
                    acc[rf][nb] = __builtin_amdgcn_mfma_f32_16x16x32_bf16(af, bq[rf], acc[rf][nb], 0, 0, 0);
            }
        }
    }
    __syncthreads();

    // dump di*D^T as bf16 [256 rows][72 shorts] (pad rows, 2-way-free banks)
    u32* dump = pool;
#pragma unroll
    for (int rf = 0; rf < 4; rf++) {
        int rn = w * 64 + rf * 16 + l15;
        float di = poolf[15104 + rn];
#pragma unroll
        for (int nb = 0; nb < 4; nb++) {
            u32 lo = (u32)f2bf(acc[rf][nb][0] * di) | ((u32)f2bf(acc[rf][nb][1] * di) << 16);
            u32 hi = (u32)f2bf(acc[rf][nb][2] * di) | ((u32)f2bf(acc[rf][nb][3] * di) << 16);
            u32* dst = dump + rn * 36 + nb * 8 + quad * 2;
            dst[0] = lo; dst[1] = hi;
        }
    }
    __syncthreads();
    f32x4 xacc[4][4];  // [ob(o16-block)][rf]
#pragma unroll
    for (int ob = 0; ob < 4; ob++)
#pragma unroll
        for (int rf = 0; rf < 4; rf++)
#pragma unroll
            for (int r = 0; r < 4; r++) xacc[ob][rf][r] = 0.0f;
#pragma unroll
    for (int ks2 = 0; ks2 < 2; ks2++) {
        short8_t b2f[4];
#pragma unroll
        for (int rf = 0; rf < 4; rf++)
            b2f[rf] = *(const short8_t*)((const unsigned short*)dump +
                        (w * 64 + rf * 16 + l15) * 72 + ks2 * 32 + quad * 8);
#pragma unroll
        for (int ob = 0; ob < 4; ob++) {
            short8_t a2 = *(const short8_t*)(W2B + (ob * 16 + l15) * 72 + ks2 * 32 + quad * 8);
#pragma unroll
            for (int rf = 0; rf < 4; rf++)
                xacc[ob][rf] = __builtin_amdgcn_mfma_f32_16x16x32_bf16(a2, b2f[rf], xacc[ob][rf], 0, 0, 0);
        }
    }
#pragma unroll
    for (int ob = 0; ob < 4; ob++) {
#pragma unroll
        for (int r = 0; r < 4; r++) {
            int o = ob * 16 + quad * 4 + r;
            float bb = poolf[15360 + o];
            float s = 0.0f;
#pragma unroll
            for (int rf = 0; rf < 4; rf++) s += fmaxf(xacc[ob][rf][r] + bb, 0.0f);
            s += __shfl_down(s, 8, 16);
            s += __shfl_down(s, 4, 16);
            s += __shfl_down(s, 2, 16);
            s += __shfl_down(s, 1, 16);
            if (l15 == 0) atomicAdd(&gsum[bt * 64 + o], s);
        }
    }
}

// K4a: per-(b,t) precompute (parallel, 128 blocks x 384 thr, 1 blk/CU).
// x[t] = bg + Wg@gm  then  gi[t][r] = bih[r] + Wih[r,:]@x.
__global__ __launch_bounds__(384, 1) void k4a_gi(const void* __restrict__ pts,
                                                 const void* __restrict__ Wg,
                                                 const void* __restrict__ bg,
                                                 const void* __restrict__ Wih,
                                                 const void* __restrict__ bih,
                                                 const float* __restrict__ gsum,
                                                 float* __restrict__ gi_ws) {
    int blk = blockIdx.x, tid = threadIdx.x;   // blk = b*32 + t
    __shared__ float s_gm[64];
    __shared__ float s_x[64];
    __shared__ int s_flag;
    bool bf = detect_bf16(pts, tid, &s_flag);
    if (tid < 64) s_gm[tid] = gsum[(size_t)blk * 64 + tid] * (1.0f / 1024.0f);
    int r = tid;
    float wv[64];
    if (bf) {
#pragma unroll
        for (int k = 0; k < 64; k++) wv[k] = bfi(((const unsigned short*)Wih)[r * 64 + k]);
    } else {
        const float4* wr = (const float4*)Wih + r * 16;
#pragma unroll
        for (int qq = 0; qq < 16; qq++) {
            float4 v = wr[qq];
            wv[4*qq] = v.x; wv[4*qq+1] = v.y; wv[4*qq+2] = v.z; wv[4*qq+3] = v.w;
        }
    }
    float br = ldf(bih, r, bf);
    float wg[64];
    if (tid < 64) {                            // wave 0: Wg row c = tid
        if (bf) {
#pragma unroll
            for (int k = 0; k < 64; k++) wg[k] = bfi(((const unsigned short*)Wg)[tid * 64 + k]);
        } else {
            const float4* wr = (const float4*)Wg + tid * 16;
#pragma unroll
            for (int qq = 0; qq < 16; qq++) {
                float4 v = wr[qq];
                wg[4*qq] = v.x; wg[4*qq+1] = v.y; wg[4*qq+2] = v.z; wg[4*qq+3] = v.w;
            }
        }
    }
    __syncthreads();                           // s_gm ready
    if (tid < 64) {
        float gmv = s_gm[tid];                 // lane c holds gm[c]
        float s0 = ldf(bg, tid, bf), s1 = 0.f, s2 = 0.f, s3 = 0.f;
#pragma unroll
        for (int k = 0; k < 64; k += 4) {
            s0 = fmaf(wg[k],     rdlane(gmv, k),     s0);
            s1 = fmaf(wg[k + 1], rdlane(gmv, k + 1), s1);
            s2 = fmaf(wg[k + 2], rdlane(gmv, k + 2), s2);
            s3 = fmaf(wg[k + 3], rdlane(gmv, k + 3), s3);
        }
        s_x[tid] = (s0 + s1) + (s2 + s3);
    }
    __syncthreads();                           // s_x ready
    float xv = s_x[tid & 63];                  // lane k holds x[k]
    float s0 = br, s1 = 0.f, s2 = 0.f, s3 = 0.f;
#pragma unroll
    for (int k = 0; k < 64; k += 4) {
        s0 = fmaf(wv[k],     rdlane(xv, k),     s0);
        s1 = fmaf(wv[k + 1], rdlane(xv, k + 1), s1);
        s2 = fmaf(wv[k + 2], rdlane(xv, k + 2), s2);
        s3 = fmaf(wv[k + 3], rdlane(xv, k + 3), s3);
    }
    gi_ws[(size_t)blk * 384 + r] = (s0 + s1) + (s2 + s3);
}

// K4b v6: third pinning attempt. R8: plain loads, VGPR=68 -> MachineLICM
// refused to hoist 64 loop-invariant loads (L2 re-fetch, 6.3MB/block, ~42us).
// R9: volatile -> SROA demoted array to scratch (VGPR=44, 56us). Now: 16 NAMED
// float4 scalars (no array to demote) + asm volatile "+v" pin per component
// (non-rematerializable, non-sinkable => must stay in VGPRs; ~110 < 256 cap).
// FMA order identical (s0..s3, k=4q+i) -> bit-identical scan.
__global__ __launch_bounds__(768, 1) void k4b_scan(const void* __restrict__ pts,
                                                   const void* __restrict__ Whh,
                                                   const void* __restrict__ bhh,
                                                   const void* __restrict__ Wf,
                                                   const void* __restrict__ bf_,
                                                   const float* __restrict__ gi_ws,
                                                   float* __restrict__ out) {
    int b = blockIdx.x, tid = threadIdx.x;
    __shared__ float s_gi[12288];      // 48 KB: [t][384]
    __shared__ float s_part[2][768];   // 6 KB, double-buffered partial dots
    __shared__ float s_hm[128];
    __shared__ int s_flag;
    bool bf = detect_bf16(pts, tid, &s_flag);
    const u32* gi_g = (const u32*)gi_ws + (size_t)b * 12288;
    u32* s_gi_u = (u32*)s_gi;
#pragma unroll
    for (int j = 0; j < 4; j++)
        gload16(gi_g + j * 3072 + tid * 4, s_gi_u + j * 3072 + tid * 4);

    int hi = (tid >= 384) ? 1 : 0;      // wave-uniform (384 = 6 waves)
    int r = tid - hi * 384;
    int lane = tid & 63;
    // Whh half-row -> 16 named float4 (no array), then asm-pin each component.
    float4 w0_, w1_, w2_, w3_, w4_, w5_, w6_, w7_,
           w8_, w9_, wA_, wB_, wC_, wD_, wE_, wF_;
    {
        int koff = hi * 64;
        if (bf) {
            const uint2* wr = (const uint2*)((const unsigned short*)Whh + r * 128 + koff);
#define LDBF(dst, ii) { uint2 uu = wr[ii]; \
            dst = make_float4(bfi(uu.x & 0xFFFFu), bfi(uu.x >> 16), \
                              bfi(uu.y & 0xFFFFu), bfi(uu.y >> 16)); }
            LDBF(w0_, 0)  LDBF(w1_, 1)  LDBF(w2_, 2)  LDBF(w3_, 3)
            LDBF(w4_, 4)  LDBF(w5_, 5)  LDBF(w6_, 6)  LDBF(w7_, 7)
            LDBF(w8_, 8)  LDBF(w9_, 9)  LDBF(wA_, 10) LDBF(wB_, 11)
            LDBF(wC_, 12) LDBF(wD_, 13) LDBF(wE_, 14) LDBF(wF_, 15)
#undef LDBF
        } else {
            const float4* wr = (const float4*)Whh + (r * 128 + koff) / 4;
            w0_ = wr[0];  w1_ = wr[1];  w2_ = wr[2];  w3_ = wr[3];
            w4_ = wr[4];  w5_ = wr[5];  w6_ = wr[6];  w7_ = wr[7];
            w8_ = wr[8];  w9_ = wr[9];  wA_ = wr[10]; wB_ = wr[11];
            wC_ = wr[12]; wD_ = wr[13]; wE_ = wr[14]; wF_ = wr[15];
        }
#define PIN(v) asm volatile("" : "+v"(v.x), "+v"(v.y), "+v"(v.z), "+v"(v.w))
        PIN(w0_); PIN(w1_); PIN(w2_); PIN(w3_);
        PIN(w4_); PIN(w5_); PIN(w6_); PIN(w7_);
        PIN(w8_); PIN(w9_); PIN(wA_); PIN(wB_);
        PIN(wC_); PIN(wD_); PIN(wE_); PIN(wF_);
#undef PIN
    }
    float bhr = hi ? 0.0f : ldf(bhh, r, bf);
    int c = hi * 64 + lane;             // the h index this thread owns/broadcasts
    float hval = 0.0f;
    float hsum = 0.0f;
    __syncthreads();                    // drains vmcnt -> s_gi ready

    for (int t = 0; t < 32; t++) {
        float gi_r = s_gi[t * 384 + c];
        float gi_z = s_gi[t * 384 + 128 + c];
        float gi_n = s_gi[t * 384 + 256 + c];
        float s0 = bhr, s1 = 0.f, s2 = 0.f, s3 = 0.f;
        // k = 4q+i: identical FMA order to R8's wh2[k] loop
#define STEPQ(q, W) \
        s0 = fmaf(W.x, rdlane(hval, 4 * q),     s0); \
        s1 = fmaf(W.y, rdlane(hval, 4 * q + 1), s1); \
        s2 = fmaf(W.z, rdlane(hval, 4 * q + 2), s2); \
        s3 = fmaf(W.w, rdlane(hval, 4 * q + 3), s3);
        STEPQ(0, w0_)  STEPQ(1, w1_)  STEPQ(2, w2_)  STEPQ(3, w3_)
        STEPQ(4, w4_)  STEPQ(5, w5_)  STEPQ(6, w6_)  STEPQ(7, w7_)
        STEPQ(8, w8_)  STEPQ(9, w9_)  STEPQ(10, wA_) STEPQ(11, wB_)
        STEPQ(12, wC_) STEPQ(13, wD_) STEPQ(14, wE_) STEPQ(15, wF_)
#undef STEPQ
        s_part[t & 1][tid] = (s0 + s1) + (s2 + s3);
        __syncthreads();                // the ONLY barrier per step
        const float* P = s_part[t & 1];
        float gr = gi_r + P[c]       + P[384 + c];
        float gz = gi_z + P[128 + c] + P[512 + c];
        float hn =        P[256 + c] + P[640 + c];
        float rr = sigm_f(gr);
        float z  = sigm_f(gz);
        float n  = tanh_f(fmaf(rr, hn, gi_n));
        hval = fmaf(z, hval - n, n);    // (1-z)*n + z*h
        hsum += hval;
    }
    if (tid < 64) s_hm[tid] = hsum * (1.0f / 32.0f);
    else if (tid >= 384 && tid < 448) s_hm[64 + lane] = hsum * (1.0f / 32.0f);
    __syncthreads();
    if (tid < 128) {
        float hm = s_hm[tid];
        s_part[0][tid]       = ldf(Wf, tid, bf) * hm;
        s_part[0][128 + tid] = ldf(Wf, 128 + tid, bf) * hm;
    }
    __syncthreads();
    if (tid < 2) {
        float s = ldf(bf_, tid, bf);
        for (int k = 0; k < 128; k++) s += s_part[0][tid * 128 + k];
        out[b * 2 + tid] = s;   // f32 output (verified R4)
    }
}

extern "C" void kernel_launch(void* const* d_in, const int* in_sizes, int n_in,
                              void* d_out, int out_size, void* d_ws, size_t ws_size,
                              hipStream_t stream) {
    const void* pts = d_in[0];
    const void* W1  = d_in[1];
    const void* b1  = d_in[2];
    const void* W2  = d_in[3];
    const void* b2  = d_in[4];
    const void* Wg  = d_in[5];
    const void* bg  = d_in[6];
    const void* Wih = d_in[7];
    const void* Whh = d_in[8];
    const void* bih = d_in[9];
    const void* bhh = d_in[10];
    const void* Wf  = d_in[11];
    const void* bf_ = d_in[12];

    // ws: dinv 512K | gsum 32K | bm 16M | x1vB 18M  (~34.5 MB)
    float* dinv = (float*)d_ws;
    float* gsum = dinv + (size_t)BT * N_PTS;
    u32*   bm   = (u32*)(gsum + BT * 64);
    u32*   x1vB = bm + (size_t)BT * 32768;
    // gi (B*T*384 f32 = 192 KB) reuses x1vB region — x1vB is dead after k3
    // (stream-serial), and k2 rewrites it fresh every iteration.
    float* gi_ws = (float*)x1vB;

    k1_bm  <<<512, 256, 0, stream>>>(pts, dinv, gsum, bm);
    k2_x1v <<<512, 256, 0, stream>>>(pts, W1, b1, dinv, bm, x1vB);
    k3_mfma<<<512, 256, 0, stream>>>(pts, W2, b2, dinv, bm, x1vB, gsum);
    k4a_gi <<<128, 384, 0, stream>>>(pts, Wg, bg, Wih, bih, gsum, gi_ws);
    k4b_scan<<<4, 768, 0, stream>>>(pts, Whh, bhh, Wf, bf_, gi_ws, (float*)d_out);
}

// Round 12
// 203.558 us; speedup vs baseline: 1.0989x; 1.0085x over previous
//
#include <hip/hip_runtime.h>
#include <hip/hip_bf16.h>
#include <math.h>

#define N_PTS 1024
#define BT    128
typedef unsigned int u32;
typedef __attribute__((ext_vector_type(8))) short short8_t;   // 8 bf16 (4 VGPRs)
typedef __attribute__((ext_vector_type(4))) float f32x4;      // MFMA acc

__device__ __forceinline__ float bfi(u32 bits16) {
    union { u32 u; float f; } v; v.u = bits16 << 16; return v.f;
}
__device__ __forceinline__ unsigned short f2bf(float f) {     // RNE f32->bf16
    union { float f; u32 u; } v; v.f = f;
    return (unsigned short)((v.u + 0x7FFFu + ((v.u >> 16) & 1u)) >> 16);
}
__device__ __forceinline__ float ldf(const void* p, int i, bool bf) {
    return bf ? bfi(((const unsigned short*)p)[i]) : ((const float*)p)[i];
}
__device__ __forceinline__ float2 ldp(const void* pbase, int j, bool bf) {
    if (bf) {
        u32 w = ((const u32*)pbase)[j];
        return make_float2(bfi(w & 0xFFFFu), bfi(w >> 16));
    }
    return ((const float2*)pbase)[j];
}
__device__ __forceinline__ bool detect_bf16(const void* pts, int tid, int* s_flag) {
    if (tid < 64) {
        u32 w = ((const u32*)pts)[tid];
        float v = bfi(w & 0xFFFFu);
        bool ok = (v >= 0.0f) && (v <= 1.0f);
        unsigned long long m = __ballot(ok);
        if (tid == 0) *s_flag = (m == 0xFFFFFFFFFFFFFFFFull) ? 1 : 0;
    }
    __syncthreads();
    return *s_flag != 0;
}
__device__ __forceinline__ bool is_nb(float px, float py, float qx, float qy) {
    float dx = px - qx, dy = py - qy;
    // ref: sqrt_rn(rn(rn(dx*dx)+rn(dy*dy))) < 0.3f  <=>  d2 < 0.09f (ulp-exact)
    float d2 = __fadd_rn(__fmul_rn(dx, dx), __fmul_rn(dy, dy));
    return d2 < 0.09f;
}
__device__ __forceinline__ const void* pts_base(const void* pts, int bt, bool bf) {
    return bf ? (const void*)((const unsigned short*)pts + (size_t)bt * N_PTS * 2)
              : (const void*)((const float*)pts + (size_t)bt * N_PTS * 2);
}
// async global->LDS, 16B per lane (lands at lds_base + lane*16) [m97 pattern]
__device__ __forceinline__ void gload16(const u32* g, u32* l) {
    __builtin_amdgcn_global_load_lds((const __attribute__((address_space(1))) u32*)g,
                                     (__attribute__((address_space(3))) u32*)l, 16, 0, 0);
}
// wave-uniform broadcast of lane `i` (compile-time) via v_readlane (VALU, not DS pipe)
__device__ __forceinline__ float rdlane(float v, int i) {
    return __int_as_float(__builtin_amdgcn_readlane(__float_as_int(v), i));
}
// fast activations via v_exp_f32 (err ~1e-6, well under absmax budget)
__device__ __forceinline__ float sigm_f(float x) {
    return __fdividef(1.0f, 1.0f + __expf(-x));
}
__device__ __forceinline__ float tanh_f(float x) {
    float e = __expf(2.0f * x);                 // +inf / 0 limits give +-1 exactly
    return 1.0f - __fdividef(2.0f, e + 1.0f);
}
// build nibble->4xbf16 LUT (16 entries x 8B). Entry n dwords:
// d0 = bf(n&1) | bf(n&2)<<16, d1 = bf(n&4) | bf(n&8)<<16. Values 0x3F80/0 ==
// bit-identical to the old per-element expand -> MFMA inputs unchanged.
__device__ __forceinline__ void build_lut(u32* slut, int tid) {
    if (tid < 16) {
        u32 d0 = ((tid & 1) ? 0x3F80u : 0u) | (((tid & 2) ? 0x3F80u : 0u) << 16);
        u32 d1 = ((tid & 4) ? 0x3F80u : 0u) | (((tid & 8) ? 0x3F80u : 0u) << 16);
        slut[2 * tid] = d0;
        slut[2 * tid + 1] = d1;
    }
}
// byte -> short8 bf16 frag via two conflict-free ds_read_b64 (16 distinct 8B
// entries hit 16 distinct bank pairs; equal nibbles broadcast).
__device__ __forceinline__ short8_t expand8(const uint2* lut2, u32 by) {
    uint2 lo = lut2[by & 15u], hi = lut2[by >> 4];
    union { uint4 u4; short8_t s8; } cv;
    cv.u4 = make_uint4(lo.x, lo.y, hi.x, hi.y);
    return cv.s8;
}

// K1: pair sweep -> adjacency bitmask bm[bt][chunk(32)][row(1024)] + cnt->dinv. Zeros gsum.
__global__ __launch_bounds__(256) void k1_bm(const void* __restrict__ pts,
                                             float* __restrict__ dinv,
                                             float* __restrict__ gsum,
                                             u32* __restrict__ bm) {
    int blk = blockIdx.x, tid = threadIdx.x;
    int bt = blk >> 2, q = blk & 3;
    __shared__ float2 sp[N_PTS];
    __shared__ int s_flag;
    bool bf = detect_bf16(pts, tid, &s_flag);
    const void* pb = pts_base(pts, bt, bf);
    for (int j = tid; j < N_PTS; j += 256) sp[j] = ldp(pb, j, bf);
    if (blk < 32) gsum[blk * 256 + tid] = 0.0f;
    __syncthreads();
    int i = q * 256 + tid;
    float px = sp[i].x, py = sp[i].y;
    const float4* sp4 = (const float4*)sp;
    u32* bmrow = bm + (size_t)bt * 32768 + i;
    int cnt = 0;
    for (int c = 0; c < 32; c++) {
        u32 m = 0;
#pragma unroll
        for (int h = 0; h < 8; h++) {
            float4 s01 = sp4[c * 16 + 2 * h], s23 = sp4[c * 16 + 2 * h + 1];
            if (is_nb(px, py, s01.x, s01.y)) m |= 1u << (4 * h);
            if (is_nb(px, py, s01.z, s01.w)) m |= 1u << (4 * h + 1);
            if (is_nb(px, py, s23.x, s23.y)) m |= 1u << (4 * h + 2);
            if (is_nb(px, py, s23.z, s23.w)) m |= 1u << (4 * h + 3);
        }
        bmrow[c * 1024] = m;
        cnt += __popc(m);
    }
    dinv[bt * N_PTS + i] = 1.0f / sqrtf((float)cnt);
}

// K2 v4: agg0 via MFMA (u hi/lo bf16) with nibble-LUT expand. phase B unchanged.
__global__ __launch_bounds__(256) void k2_x1v(const void* __restrict__ pts,
                                              const void* __restrict__ W1,
                                              const void* __restrict__ b1,
                                              const float* __restrict__ dinv,
                                              const u32* __restrict__ bm,
                                              u32* __restrict__ x1vB) {
    int blk = blockIdx.x, tid = threadIdx.x;
    int bt = blk >> 2, q = blk & 3;
    __shared__ u32 sbm[8192];                    // 32 chunks x 256 rows
    __shared__ unsigned short u_lds[4][1032];    // {xh,yh,xl,yl} x 1024 (+pad)
    __shared__ float2 sax[256];
    __shared__ float  sdl[256];
    __shared__ u32 slut[32];
    __shared__ int s_flag;
    bool bf = detect_bf16(pts, tid, &s_flag);
    build_lut(slut, tid);
    const void* pb = pts_base(pts, bt, bf);
    for (int j = tid; j < N_PTS; j += 256) {
        float2 p = ldp(pb, j, bf);
        float d = dinv[bt * N_PTS + j];
        float ux = d * p.x, uy = d * p.y;
        unsigned short hx = f2bf(ux), hy = f2bf(uy);
        u_lds[0][j] = hx;
        u_lds[1][j] = hy;
        u_lds[2][j] = f2bf(ux - bfi(hx));
        u_lds[3][j] = f2bf(uy - bfi(hy));
    }
    const u32* bg_ = bm + (size_t)bt * 32768 + q * 256;
    for (int idx = tid; idx < 8192; idx += 256) {
        int c = idx >> 8, r = idx & 255;
        sbm[idx] = bg_[c * 1024 + r];
    }
    sdl[tid] = dinv[bt * N_PTS + q * 256 + tid];
    __syncthreads();

    int lane = tid & 63, w = tid >> 6;
    int l15 = lane & 15, quad = lane >> 4;
    f32x4 acc[4];   // [rf] : D rows = graph rows rf*16+quad*4+reg, col l15 = comp
#pragma unroll
    for (int rf = 0; rf < 4; rf++)
#pragma unroll
        for (int r = 0; r < 4; r++) acc[rf][r] = 0.0f;

    const unsigned short* urow = &u_lds[l15 & 3][0];
    const uint2* lut2 = (const uint2*)slut;
    for (int c = 0; c < 32; c++) {
        short8_t bu = *(const short8_t*)(urow + c * 32 + quad * 8);
#pragma unroll
        for (int rf = 0; rf < 4; rf++) {
            u32 mw = sbm[c * 256 + w * 64 + rf * 16 + l15];
            u32 by = (mw >> (quad * 8)) & 0xFFu;
            acc[rf] = __builtin_amdgcn_mfma_f32_16x16x32_bf16(expand8(lut2, by), bu, acc[rf], 0, 0, 0);
        }
    }
    // combine hi+lo (l15: 0 gets 2's acc = x_lo, 1 gets 3's = y_lo); scale by di
#pragma unroll
    for (int rf = 0; rf < 4; rf++) {
#pragma unroll
        for (int r = 0; r < 4; r++) {
            float vsum = acc[rf][r] + __shfl_xor(acc[rf][r], 2, 64);
            int row = w * 64 + rf * 16 + quad * 4 + r;
            float sc = vsum * sdl[row];
            if (l15 == 0)      sax[row].x = sc;
            else if (l15 == 1) sax[row].y = sc;
        }
    }
    __syncthreads();
    // phase B: tiles q*4..q*4+4; thread = (ch, wave=jj-quarter)  [unchanged]
    int ch = tid & 63, wq = tid >> 6;
    float w0 = ldf(W1, 2 * ch, bf), w1v = ldf(W1, 2 * ch + 1, bf), bb = ldf(b1, ch, bf);
    for (int tt = 0; tt < 4; tt++) {
        u32 ow[8];
#pragma unroll
        for (int k2i = 0; k2i < 8; k2i++) {
            int lj = tt * 64 + wq * 16 + 2 * k2i;
            float2 a0 = sax[lj], a1 = sax[lj + 1];
            float v0 = sdl[lj]     * fmaxf(fmaf(w0, a0.x, fmaf(w1v, a0.y, bb)), 0.0f);
            float v1 = sdl[lj + 1] * fmaxf(fmaf(w0, a1.x, fmaf(w1v, a1.y, bb)), 0.0f);
            ow[k2i] = (u32)f2bf(v0) | ((u32)f2bf(v1) << 16);
        }
        u32* dst = x1vB + ((size_t)(bt * 16 + q * 4 + tt) * 64 + ch) * 36 + wq * 8;
        *(uint4*)dst = make_uint4(ow[0], ow[1], ow[2], ow[3]);
        *(uint4*)(dst + 4) = make_uint4(ow[4], ow[5], ow[6], ow[7]);
    }
}

// K3: D^T = x1v^T @ A with nibble-LUT expand; dbuf gload16; W2 epilogue.
__global__ __launch_bounds__(256) void k3_mfma(const void* __restrict__ pts,
                                               const void* __restrict__ W2,
                                               const void* __restrict__ b2,
                                               const float* __restrict__ dinv,
                                               const u32* __restrict__ bm,
                                               const u32* __restrict__ x1vB,
                                               float* __restrict__ gsum) {
    // pool dwords: sbm[0,8192) xf0[8192,10496) xf1[10496,12800) W2B[12800,15104)
    // sdi[15104,15360) sb2[15360,15424). dump overlays [0,9216) post-K-loop.
    __shared__ u32 pool[15424];
    __shared__ u32 slut[32];
    __shared__ int s_flag;
    float* poolf = (float*)pool;
    int tid = threadIdx.x, lane = tid & 63, w = tid >> 6;
    int l15 = lane & 15, quad = lane >> 4;
    int blk = blockIdx.x, bt = blk & 127, rowblk = blk >> 7;
    bool bf = detect_bf16(pts, tid, &s_flag);
    build_lut(slut, tid);

    const u32* xg = x1vB + (size_t)bt * 36864;   // 16 tiles * 2304 dw
    for (int it = w; it < 9; it += 4)            // prefetch tile 0 -> xf0
        gload16(xg + it * 256 + lane * 4, pool + 8192 + it * 256 + lane * 4);

    const u32* bg_ = bm + (size_t)bt * 32768 + rowblk * 256;
    for (int idx = tid; idx < 8192; idx += 256) {
        int c = idx >> 8, r = idx & 255;
        pool[idx] = bg_[c * 1024 + r];
    }
    unsigned short* W2B = (unsigned short*)(pool + 12800);
    for (int idx = tid; idx < 4096; idx += 256) {
        int o = idx >> 6, c = idx & 63;
        W2B[o * 72 + c] = f2bf(ldf(W2, idx, bf));
    }
    if (tid < 256) poolf[15104 + tid] = dinv[bt * N_PTS + rowblk * 256 + tid];
    if (tid < 64)  poolf[15360 + tid] = ldf(b2, tid, bf);

    f32x4 acc[4][4];   // [rf(row16-block)][nb(ch16-block)]
#pragma unroll
    for (int rf = 0; rf < 4; rf++)
#pragma unroll
        for (int nb = 0; nb < 4; nb++)
#pragma unroll
            for (int r = 0; r < 4; r++) acc[rf][nb][r] = 0.0f;

    const uint2* lut2 = (const uint2*)slut;
    for (int t = 0; t < 16; t++) {
        __syncthreads();   // drains vmcnt -> current buf ready
        if (t + 1 < 16) {
            u32* dst = pool + ((t & 1) ? 8192 : 10496);
            const u32* src = xg + (t + 1) * 2304;
            for (int it = w; it < 9; it += 4)
                gload16(src + it * 256 + lane * 4, dst + it * 256 + lane * 4);
        }
        const unsigned short* xf = (const unsigned short*)(pool + ((t & 1) ? 10496 : 8192));
#pragma unroll
        for (int ks = 0; ks < 2; ks++) {
            short8_t bq[4];
#pragma unroll
            for (int rf = 0; rf < 4; rf++) {
                u32 mw = pool[(2 * t + ks) * 256 + w * 64 + rf * 16 + l15];
                u32 by = (mw >> (quad * 8)) & 0xFFu;
                bq[rf] = expand8(lut2, by);
            }
#pragma unroll
            for (int nb = 0; nb < 4; nb++) {
                short8_t af = *(const short8_t*)(xf + (nb * 16 + l15) * 72 + ks * 32 + quad * 8);
#pragma unroll
                for (int rf = 0; rf < 4; rf++)
                    acc[rf][nb] = __builtin_amdgcn_mfma_f32_16x16x32_bf16(af, bq[rf], acc[rf][nb], 0, 0, 0);
            }
        }
    }
    __syncthreads();

    // dump di*D^T as bf16 [256 rows][72 shorts] (pad rows, 2-way-free banks)
    u32* dump = pool;
#pragma unroll
    for (int rf = 0; rf < 4; rf++) {
        int rn = w * 64 + rf * 16 + l15;
        float di = poolf[15104 + rn];
#pragma unroll
        for (int nb = 0; nb < 4; nb++) {
            u32 lo = (u32)f2bf(acc[rf][nb][0] * di) | ((u32)f2bf(acc[rf][nb][1] * di) << 16);
            u32 hi = (u32)f2bf(acc[rf][nb][2] * di) | ((u32)f2bf(acc[rf][nb][3] * di) << 16);
            u32* dst = dump + rn * 36 + nb * 8 + quad * 2;
            dst[0] = lo; dst[1] = hi;
        }
    }
    __syncthreads();
    f32x4 xacc[4][4];  // [ob(o16-block)][rf]
#pragma unroll
    for (int ob = 0; ob < 4; ob++)
#pragma unroll
        for (int rf = 0; rf < 4; rf++)
#pragma unroll
            for (int r = 0; r < 4; r++) xacc[ob][rf][r] = 0.0f;
#pragma unroll
    for (int ks2 = 0; ks2 < 2; ks2++) {
        short8_t b2f[4];
#pragma unroll
        for (int rf = 0; rf < 4; rf++)
            b2f[rf] = *(const short8_t*)((const unsigned short*)dump +
                        (w * 64 + rf * 16 + l15) * 72 + ks2 * 32 + quad * 8);
#pragma unroll
        for (int ob = 0; ob < 4; ob++) {
            short8_t a2 = *(const short8_t*)(W2B + (ob * 16 + l15) * 72 + ks2 * 32 + quad * 8);
#pragma unroll
            for (int rf = 0; rf < 4; rf++)
                xacc[ob][rf] = __builtin_amdgcn_mfma_f32_16x16x32_bf16(a2, b2f[rf], xacc[ob][rf], 0, 0, 0);
        }
    }
#pragma unroll
    for (int ob = 0; ob < 4; ob++) {
#pragma unroll
        for (int r = 0; r < 4; r++) {
            int o = ob * 16 + quad * 4 + r;
            float bb = poolf[15360 + o];
            float s = 0.0f;
#pragma unroll
            for (int rf = 0; rf < 4; rf++) s += fmaxf(xacc[ob][rf][r] + bb, 0.0f);
            s += __shfl_down(s, 8, 16);
            s += __shfl_down(s, 4, 16);
            s += __shfl_down(s, 2, 16);
            s += __shfl_down(s, 1, 16);
            if (l15 == 0) atomicAdd(&gsum[bt * 64 + o], s);
        }
    }
}

// K4a: per-(b,t) precompute (parallel, 128 blocks x 384 thr, 1 blk/CU).
// x[t] = bg + Wg@gm  then  gi[t][r] = bih[r] + Wih[r,:]@x.
__global__ __launch_bounds__(384, 1) void k4a_gi(const void* __restrict__ pts,
                                                 const void* __restrict__ Wg,
                                                 const void* __restrict__ bg,
                                                 const void* __restrict__ Wih,
                                                 const void* __restrict__ bih,
                                                 const float* __restrict__ gsum,
                                                 float* __restrict__ gi_ws) {
    int blk = blockIdx.x, tid = threadIdx.x;   // blk = b*32 + t
    __shared__ float s_gm[64];
    __shared__ float s_x[64];
    __shared__ int s_flag;
    bool bf = detect_bf16(pts, tid, &s_flag);
    if (tid < 64) s_gm[tid] = gsum[(size_t)blk * 64 + tid] * (1.0f / 1024.0f);
    int r = tid;
    float wv[64];
    if (bf) {
#pragma unroll
        for (int k = 0; k < 64; k++) wv[k] = bfi(((const unsigned short*)Wih)[r * 64 + k]);
    } else {
        const float4* wr = (const float4*)Wih + r * 16;
#pragma unroll
        for (int qq = 0; qq < 16; qq++) {
            float4 v = wr[qq];
            wv[4*qq] = v.x; wv[4*qq+1] = v.y; wv[4*qq+2] = v.z; wv[4*qq+3] = v.w;
        }
    }
    float br = ldf(bih, r, bf);
    float wg[64];
    if (tid < 64) {                            // wave 0: Wg row c = tid
        if (bf) {
#pragma unroll
            for (int k = 0; k < 64; k++) wg[k] = bfi(((const unsigned short*)Wg)[tid * 64 + k]);
        } else {
            const float4* wr = (const float4*)Wg + tid * 16;
#pragma unroll
            for (int qq = 0; qq < 16; qq++) {
                float4 v = wr[qq];
                wg[4*qq] = v.x; wg[4*qq+1] = v.y; wg[4*qq+2] = v.z; wg[4*qq+3] = v.w;
            }
        }
    }
    __syncthreads();                           // s_gm ready
    if (tid < 64) {
        float gmv = s_gm[tid];                 // lane c holds gm[c]
        float s0 = ldf(bg, tid, bf), s1 = 0.f, s2 = 0.f, s3 = 0.f;
#pragma unroll
        for (int k = 0; k < 64; k += 4) {
            s0 = fmaf(wg[k],     rdlane(gmv, k),     s0);
            s1 = fmaf(wg[k + 1], rdlane(gmv, k + 1), s1);
            s2 = fmaf(wg[k + 2], rdlane(gmv, k + 2), s2);
            s3 = fmaf(wg[k + 3], rdlane(gmv, k + 3), s3);
        }
        s_x[tid] = (s0 + s1) + (s2 + s3);
    }
    __syncthreads();                           // s_x ready
    float xv = s_x[tid & 63];                  // lane k holds x[k]
    float s0 = br, s1 = 0.f, s2 = 0.f, s3 = 0.f;
#pragma unroll
    for (int k = 0; k < 64; k += 4) {
        s0 = fmaf(wv[k],     rdlane(xv, k),     s0);
        s1 = fmaf(wv[k + 1], rdlane(xv, k + 1), s1);
        s2 = fmaf(wv[k + 2], rdlane(xv, k + 2), s2);
        s3 = fmaf(wv[k + 3], rdlane(xv, k + 3), s3);
    }
    gi_ws[(size_t)blk * 384 + r] = (s0 + s1) + (s2 + s3);
}

// K4b v7: MFMA scan. Three register-pinning attempts (R8 plain/R9 volatile/
// R11 asm-pin) all failed to make the 768-thread readlane-matvec fast; the
// structure itself goes. gh = Whh@h via the k2-verified MFMA pattern:
// opA lane(l15,quad)[i] = M[l15][k0+quad*8+i], opB[i] = N[l15][k0+quad*8+i]
// => D lane(l15,quad)[r] = sum_k M[quad*4+r][k]*N[l15][k].
// Whh as hi/lo bf16 A-frags resident in VGPRs (built by arithmetic -> not
// rematerializable); h as bf16 hi/lo in LDS, B-frag independent of l15 (all
// 16 D-cols = gh); 3-term product (lo*lo ~2^-16 dropped). 24 MFMA/wave/step,
// gates on 2 waves. Whole s_part/readlane machinery deleted.
__global__ __launch_bounds__(768, 1) void k4b_scan(const void* __restrict__ pts,
                                                   const void* __restrict__ Whh,
                                                   const void* __restrict__ bhh,
                                                   const void* __restrict__ Wf,
                                                   const void* __restrict__ bf_,
                                                   const float* __restrict__ gi_ws,
                                                   float* __restrict__ out) {
    int b = blockIdx.x, tid = threadIdx.x;
    __shared__ float s_gi[12288];      // 48 KB: [t][384]
    __shared__ float gh_lds[384];
    __shared__ unsigned short h_hi[128] __attribute__((aligned(16)));
    __shared__ unsigned short h_lo[128] __attribute__((aligned(16)));
    __shared__ float s_red[256];
    __shared__ int s_flag;
    bool bf = detect_bf16(pts, tid, &s_flag);
    const u32* gi_g = (const u32*)gi_ws + (size_t)b * 12288;
    u32* s_gi_u = (u32*)s_gi;
#pragma unroll
    for (int j = 0; j < 4; j++)
        gload16(gi_g + j * 3072 + tid * 4, s_gi_u + j * 3072 + tid * 4);

    int lane = tid & 63, w = tid >> 6;
    int l15 = lane & 15, quad = lane >> 4;
    // Whh -> MFMA A-frags: wave w owns row-tiles 2w, 2w+1 (rows T*16+l15),
    // 4 k-slices, hi/lo bf16. 16 short8 = 64 VGPR, resident for the scan.
    short8_t whi[2][4], wlo[2][4];
#pragma unroll
    for (int tt = 0; tt < 2; tt++) {
        int row = (2 * w + tt) * 16 + l15;
#pragma unroll
        for (int s = 0; s < 4; s++) {
            union { uint4 u4; short8_t s8; } cv, cl;
            if (bf) {
                cv.u4 = *(const uint4*)((const unsigned short*)Whh + row * 128 + s * 32 + quad * 8);
                cl.u4 = make_uint4(0u, 0u, 0u, 0u);   // bf16 input: residual = 0
            } else {
                const float* wp = (const float*)Whh + row * 128 + s * 32 + quad * 8;
                float4 a = ((const float4*)wp)[0], b4 = ((const float4*)wp)[1];
                float v[8] = {a.x, a.y, a.z, a.w, b4.x, b4.y, b4.z, b4.w};
                unsigned short hh_[8], ll_[8];
#pragma unroll
                for (int i = 0; i < 8; i++) {
                    hh_[i] = f2bf(v[i]);
                    ll_[i] = f2bf(v[i] - bfi(hh_[i]));
                }
                cv.u4 = make_uint4((u32)hh_[0] | ((u32)hh_[1] << 16),
                                   (u32)hh_[2] | ((u32)hh_[3] << 16),
                                   (u32)hh_[4] | ((u32)hh_[5] << 16),
                                   (u32)hh_[6] | ((u32)hh_[7] << 16));
                cl.u4 = make_uint4((u32)ll_[0] | ((u32)ll_[1] << 16),
                                   (u32)ll_[2] | ((u32)ll_[3] << 16),
                                   (u32)ll_[4] | ((u32)ll_[5] << 16),
                                   (u32)ll_[6] | ((u32)ll_[7] << 16));
            }
            whi[tt][s] = cv.s8;
            wlo[tt][s] = cl.s8;
        }
    }
    // gates state (threads 0..127 canonical; c = tid)
    float bhh_r = 0.f, bhh_z = 0.f, bhh_n = 0.f;
    if (tid < 128) {
        bhh_r = ldf(bhh, tid, bf);
        bhh_z = ldf(bhh, 128 + tid, bf);
        bhh_n = ldf(bhh, 256 + tid, bf);
        h_hi[tid] = 0; h_lo[tid] = 0;          // h0 = 0
    }
    float hval = 0.0f, hsum = 0.0f;
    __syncthreads();                           // drains gloads; h/frags ready

    for (int t = 0; t < 32; t++) {
        // --- matvec: all 12 waves. B-frags broadcast from h LDS (bank-free).
        short8_t hh[4], hl[4];
#pragma unroll
        for (int s = 0; s < 4; s++) {
            hh[s] = *(const short8_t*)(h_hi + s * 32 + quad * 8);
            hl[s] = *(const short8_t*)(h_lo + s * 32 + quad * 8);
        }
        f32x4 acc0, acc1;
#pragma unroll
        for (int r = 0; r < 4; r++) { acc0[r] = 0.0f; acc1[r] = 0.0f; }
#pragma unroll
        for (int s = 0; s < 4; s++) {
            acc0 = __builtin_amdgcn_mfma_f32_16x16x32_bf16(wlo[0][s], hh[s], acc0, 0, 0, 0);
            acc0 = __builtin_amdgcn_mfma_f32_16x16x32_bf16(whi[0][s], hl[s], acc0, 0, 0, 0);
            acc0 = __builtin_amdgcn_mfma_f32_16x16x32_bf16(whi[0][s], hh[s], acc0, 0, 0, 0);
            acc1 = __builtin_amdgcn_mfma_f32_16x16x32_bf16(wlo[1][s], hh[s], acc1, 0, 0, 0);
            acc1 = __builtin_amdgcn_mfma_f32_16x16x32_bf16(whi[1][s], hl[s], acc1, 0, 0, 0);
            acc1 = __builtin_amdgcn_mfma_f32_16x16x32_bf16(whi[1][s], hh[s], acc1, 0, 0, 0);
        }
        if (l15 == 0) {                        // all 16 D-cols equal -> col 0
#pragma unroll
            for (int r = 0; r < 4; r++) {
                gh_lds[(2 * w) * 16 + quad * 4 + r]     = acc0[r];
                gh_lds[(2 * w + 1) * 16 + quad * 4 + r] = acc1[r];
            }
        }
        __syncthreads();                       // gh ready
        if (tid < 128) {
            int c = tid;
            float gi_r = s_gi[t * 384 + c];
            float gi_z = s_gi[t * 384 + 128 + c];
            float gi_n = s_gi[t * 384 + 256 + c];
            float gr = gi_r + (gh_lds[c] + bhh_r);
            float gz = gi_z + (gh_lds[128 + c] + bhh_z);
            float hn = gh_lds[256 + c] + bhh_n;
            float rr = sigm_f(gr);
            float z  = sigm_f(gz);
            float n  = tanh_f(fmaf(rr, hn, gi_n));
            hval = fmaf(z, hval - n, n);       // (1-z)*n + z*h
            hsum += hval;
            unsigned short hb = f2bf(hval);
            h_hi[c] = hb;
            h_lo[c] = f2bf(hval - bfi(hb));
        }
        __syncthreads();                       // h ready for next step
    }
    if (tid < 128) {
        float hm = hsum * (1.0f / 32.0f);
        s_red[tid]       = ldf(Wf, tid, bf) * hm;
        s_red[128 + tid] = ldf(Wf, 128 + tid, bf) * hm;
    }
    __syncthreads();
    if (tid < 2) {
        float s = ldf(bf_, tid, bf);
        for (int k = 0; k < 128; k++) s += s_red[tid * 128 + k];
        out[b * 2 + tid] = s;   // f32 output (verified R4)
    }
}

extern "C" void kernel_launch(void* const* d_in, const int* in_sizes, int n_in,
                              void* d_out, int out_size, void* d_ws, size_t ws_size,
                              hipStream_t stream) {
    const void* pts = d_in[0];
    const void* W1  = d_in[1];
    const void* b1  = d_in[2];
    const void* W2  = d_in[3];
    const void* b2  = d_in[4];
    const void* Wg  = d_in[5];
    const void* bg  = d_in[6];
    const void* Wih = d_in[7];
    const void* Whh = d_in[8];
    const void* bih = d_in[9];
    const void* bhh = d_in[10];
    const void* Wf  = d_in[11];
    const void* bf_ = d_in[12];

    // ws: dinv 512K | gsum 32K | bm 16M | x1vB 18M  (~34.5 MB)
    float* dinv = (float*)d_ws;
    float* gsum = dinv + (size_t)BT * N_PTS;
    u32*   bm   = (u32*)(gsum + BT * 64);
    u32*   x1vB = bm + (size_t)BT * 32768;
    // gi (B*T*384 f32 = 192 KB) reuses x1vB region — x1vB is dead after k3
    // (stream-serial), and k2 rewrites it fresh every iteration.
    float* gi_ws = (float*)x1vB;

    k1_bm  <<<512, 256, 0, stream>>>(pts, dinv, gsum, bm);
    k2_x1v <<<512, 256, 0, stream>>>(pts, W1, b1, dinv, bm, x1vB);
    k3_mfma<<<512, 256, 0, stream>>>(pts, W2, b2, dinv, bm, x1vB, gsum);
    k4a_gi <<<128, 384, 0, stream>>>(pts, Wg, bg, Wih, bih, gsum, gi_ws);
    k4b_scan<<<4, 768, 0, stream>>>(pts, Whh, bhh, Wf, bf_, gi_ws, (float*)d_out);
}

// Round 13
// 202.404 us; speedup vs baseline: 1.1052x; 1.0057x over previous
//
#include <hip/hip_runtime.h>
#include <hip/hip_bf16.h>
#include <math.h>

#define N_PTS 1024
#define BT    128
typedef unsigned int u32;
typedef __attribute__((ext_vector_type(8))) short short8_t;   // 8 bf16 (4 VGPRs)
typedef __attribute__((ext_vector_type(4))) float f32x4;      // MFMA acc

__device__ __forceinline__ float bfi(u32 bits16) {
    union { u32 u; float f; } v; v.u = bits16 << 16; return v.f;
}
__device__ __forceinline__ unsigned short f2bf(float f) {     // RNE f32->bf16
    union { float f; u32 u; } v; v.f = f;
    return (unsigned short)((v.u + 0x7FFFu + ((v.u >> 16) & 1u)) >> 16);
}
__device__ __forceinline__ float ldf(const void* p, int i, bool bf) {
    return bf ? bfi(((const unsigned short*)p)[i]) : ((const float*)p)[i];
}
__device__ __forceinline__ float2 ldp(const void* pbase, int j, bool bf) {
    if (bf) {
        u32 w = ((const u32*)pbase)[j];
        return make_float2(bfi(w & 0xFFFFu), bfi(w >> 16));
    }
    return ((const float2*)pbase)[j];
}
__device__ __forceinline__ bool detect_bf16(const void* pts, int tid, int* s_flag) {
    if (tid < 64) {
        u32 w = ((const u32*)pts)[tid];
        float v = bfi(w & 0xFFFFu);
        bool ok = (v >= 0.0f) && (v <= 1.0f);
        unsigned long long m = __ballot(ok);
        if (tid == 0) *s_flag = (m == 0xFFFFFFFFFFFFFFFFull) ? 1 : 0;
    }
    __syncthreads();
    return *s_flag != 0;
}
__device__ __forceinline__ bool is_nb(float px, float py, float qx, float qy) {
    float dx = px - qx, dy = py - qy;
    // ref: sqrt_rn(rn(rn(dx*dx)+rn(dy*dy))) < 0.3f  <=>  d2 < 0.09f (ulp-exact)
    float d2 = __fadd_rn(__fmul_rn(dx, dx), __fmul_rn(dy, dy));
    return d2 < 0.09f;
}
__device__ __forceinline__ const void* pts_base(const void* pts, int bt, bool bf) {
    return bf ? (const void*)((const unsigned short*)pts + (size_t)bt * N_PTS * 2)
              : (const void*)((const float*)pts + (size_t)bt * N_PTS * 2);
}
// async global->LDS, 16B per lane (lands at lds_base + lane*16) [m97 pattern]
__device__ __forceinline__ void gload16(const u32* g, u32* l) {
    __builtin_amdgcn_global_load_lds((const __attribute__((address_space(1))) u32*)g,
                                     (__attribute__((address_space(3))) u32*)l, 16, 0, 0);
}
// wave-uniform broadcast of lane `i` (compile-time) via v_readlane (VALU, not DS pipe)
__device__ __forceinline__ float rdlane(float v, int i) {
    return __int_as_float(__builtin_amdgcn_readlane(__float_as_int(v), i));
}
// fast activations via v_exp_f32 (err ~1e-6, well under absmax budget)
__device__ __forceinline__ float sigm_f(float x) {
    return __fdividef(1.0f, 1.0f + __expf(-x));
}
__device__ __forceinline__ float tanh_f(float x) {
    float e = __expf(2.0f * x);                 // +inf / 0 limits give +-1 exactly
    return 1.0f - __fdividef(2.0f, e + 1.0f);
}
// build nibble->4xbf16 LUT (16 entries x 8B). Values 0x3F80/0 == bit-identical
// to per-element expand -> MFMA inputs unchanged.
__device__ __forceinline__ void build_lut(u32* slut, int tid) {
    if (tid < 16) {
        u32 d0 = ((tid & 1) ? 0x3F80u : 0u) | (((tid & 2) ? 0x3F80u : 0u) << 16);
        u32 d1 = ((tid & 4) ? 0x3F80u : 0u) | (((tid & 8) ? 0x3F80u : 0u) << 16);
        slut[2 * tid] = d0;
        slut[2 * tid + 1] = d1;
    }
}
// byte -> short8 bf16 frag via two conflict-free ds_read_b64.
__device__ __forceinline__ short8_t expand8(const uint2* lut2, u32 by) {
    uint2 lo = lut2[by & 15u], hi = lut2[by >> 4];
    union { uint4 u4; short8_t s8; } cv;
    cv.u4 = make_uint4(lo.x, lo.y, hi.x, hi.y);
    return cv.s8;
}

// K1: pair sweep -> adjacency bitmask bm[bt][chunk(32)][row(1024)] + cnt->dinv. Zeros gsum.
__global__ __launch_bounds__(256) void k1_bm(const void* __restrict__ pts,
                                             float* __restrict__ dinv,
                                             float* __restrict__ gsum,
                                             u32* __restrict__ bm) {
    int blk = blockIdx.x, tid = threadIdx.x;
    int bt = blk >> 2, q = blk & 3;
    __shared__ float2 sp[N_PTS];
    __shared__ int s_flag;
    bool bf = detect_bf16(pts, tid, &s_flag);
    const void* pb = pts_base(pts, bt, bf);
    for (int j = tid; j < N_PTS; j += 256) sp[j] = ldp(pb, j, bf);
    if (blk < 32) gsum[blk * 256 + tid] = 0.0f;
    __syncthreads();
    int i = q * 256 + tid;
    float px = sp[i].x, py = sp[i].y;
    const float4* sp4 = (const float4*)sp;
    u32* bmrow = bm + (size_t)bt * 32768 + i;
    int cnt = 0;
    for (int c = 0; c < 32; c++) {
        u32 m = 0;
#pragma unroll
        for (int h = 0; h < 8; h++) {
            float4 s01 = sp4[c * 16 + 2 * h], s23 = sp4[c * 16 + 2 * h + 1];
            if (is_nb(px, py, s01.x, s01.y)) m |= 1u << (4 * h);
            if (is_nb(px, py, s01.z, s01.w)) m |= 1u << (4 * h + 1);
            if (is_nb(px, py, s23.x, s23.y)) m |= 1u << (4 * h + 2);
            if (is_nb(px, py, s23.z, s23.w)) m |= 1u << (4 * h + 3);
        }
        bmrow[c * 1024] = m;
        cnt += __popc(m);
    }
    dinv[bt * N_PTS + i] = 1.0f / sqrtf((float)cnt);
}

// K2 v5: agg0 MFMA only; writes sax (f32x2, 2KB/block) to GLOBAL instead of
// materializing the 18MB x1vB (phase-B moved into k3 — kills the 18MB write
// + 75MB aggregate re-read). sax values bit-identical to v4's LDS sax.
__global__ __launch_bounds__(256) void k2_sax(const void* __restrict__ pts,
                                              const float* __restrict__ dinv,
                                              const u32* __restrict__ bm,
                                              float* __restrict__ sax_g) {
    int blk = blockIdx.x, tid = threadIdx.x;
    int bt = blk >> 2, q = blk & 3;
    __shared__ u32 sbm[8192];                    // 32 chunks x 256 rows
    __shared__ unsigned short u_lds[4][1032];    // {xh,yh,xl,yl} x 1024 (+pad)
    __shared__ float  sdl[256];
    __shared__ u32 slut[32];
    __shared__ int s_flag;
    bool bf = detect_bf16(pts, tid, &s_flag);
    build_lut(slut, tid);
    const void* pb = pts_base(pts, bt, bf);
    for (int j = tid; j < N_PTS; j += 256) {
        float2 p = ldp(pb, j, bf);
        float d = dinv[bt * N_PTS + j];
        float ux = d * p.x, uy = d * p.y;
        unsigned short hx = f2bf(ux), hy = f2bf(uy);
        u_lds[0][j] = hx;
        u_lds[1][j] = hy;
        u_lds[2][j] = f2bf(ux - bfi(hx));
        u_lds[3][j] = f2bf(uy - bfi(hy));
    }
    const u32* bg_ = bm + (size_t)bt * 32768 + q * 256;
    for (int idx = tid; idx < 8192; idx += 256) {
        int c = idx >> 8, r = idx & 255;
        sbm[idx] = bg_[c * 1024 + r];
    }
    sdl[tid] = dinv[bt * N_PTS + q * 256 + tid];
    __syncthreads();

    int lane = tid & 63, w = tid >> 6;
    int l15 = lane & 15, quad = lane >> 4;
    f32x4 acc[4];
#pragma unroll
    for (int rf = 0; rf < 4; rf++)
#pragma unroll
        for (int r = 0; r < 4; r++) acc[rf][r] = 0.0f;

    const unsigned short* urow = &u_lds[l15 & 3][0];
    const uint2* lut2 = (const uint2*)slut;
    for (int c = 0; c < 32; c++) {
        short8_t bu = *(const short8_t*)(urow + c * 32 + quad * 8);
#pragma unroll
        for (int rf = 0; rf < 4; rf++) {
            u32 mw = sbm[c * 256 + w * 64 + rf * 16 + l15];
            u32 by = (mw >> (quad * 8)) & 0xFFu;
            acc[rf] = __builtin_amdgcn_mfma_f32_16x16x32_bf16(expand8(lut2, by), bu, acc[rf], 0, 0, 0);
        }
    }
    // combine hi+lo; scale by di; write f32 to global (exact)
    float2* srow = (float2*)sax_g + (size_t)bt * 1024 + q * 256;
#pragma unroll
    for (int rf = 0; rf < 4; rf++) {
#pragma unroll
        for (int r = 0; r < 4; r++) {
            float vsum = acc[rf][r] + __shfl_xor(acc[rf][r], 2, 64);
            int row = w * 64 + rf * 16 + quad * 4 + r;
            float sc = vsum * sdl[row];
            if (l15 == 0)      srow[row].x = sc;
            else if (l15 == 1) srow[row].y = sc;
        }
    }
}

// K3 v2: per-tile phase-B (R7-k23 code, bit-identical x1v) into LDS, then
// D^T MFMA with LUT expand; W2 epilogue. No x1vB, no gload16 dbuf.
// pool (dw): sbm[0,8192) xt[8192,10496) saxl[10496,12544) sdll[12544,13568)
// W2B[13568,15872) sb2[15872,15936). dump overlays [0,4608). 62.25KB, 2 blk/CU.
__global__ __launch_bounds__(256) void k3_mfma(const void* __restrict__ pts,
                                               const void* __restrict__ W1,
                                               const void* __restrict__ b1,
                                               const void* __restrict__ W2,
                                               const void* __restrict__ b2,
                                               const float* __restrict__ dinv,
                                               const u32* __restrict__ bm,
                                               const float* __restrict__ sax_g,
                                               float* __restrict__ gsum) {
    __shared__ u32 pool[15936];
    __shared__ u32 slut[32];
    __shared__ int s_flag;
    float* poolf = (float*)pool;
    int tid = threadIdx.x, lane = tid & 63, w = tid >> 6;
    int l15 = lane & 15, quad = lane >> 4;
    int blk = blockIdx.x, bt = blk & 127, rowblk = blk >> 7;
    bool bf = detect_bf16(pts, tid, &s_flag);
    build_lut(slut, tid);

    // stage sax (all 1024 rows, f32x2) + sdl + bm(rowblk) + W2B + b2
    float2* saxl = (float2*)(pool + 10496);
    const float2* sg = (const float2*)sax_g + (size_t)bt * 1024;
    for (int j = tid; j < 1024; j += 256) {
        saxl[j] = sg[j];
        poolf[12544 + j] = dinv[bt * N_PTS + j];
    }
    const u32* bg_ = bm + (size_t)bt * 32768 + rowblk * 256;
    for (int idx = tid; idx < 8192; idx += 256) {
        int c = idx >> 8, r = idx & 255;
        pool[idx] = bg_[c * 1024 + r];
    }
    unsigned short* W2B = (unsigned short*)(pool + 13568);
    for (int idx = tid; idx < 4096; idx += 256) {
        int o = idx >> 6, c = idx & 63;
        W2B[o * 72 + c] = f2bf(ldf(W2, idx, bf));
    }
    if (tid < 64) poolf[15872 + tid] = ldf(b2, tid, bf);

    f32x4 acc[4][4];   // [rf(row16-block)][nb(ch16-block)]
#pragma unroll
    for (int rf = 0; rf < 4; rf++)
#pragma unroll
        for (int nb = 0; nb < 4; nb++)
#pragma unroll
            for (int r = 0; r < 4; r++) acc[rf][nb][r] = 0.0f;

    unsigned short* xt = (unsigned short*)(pool + 8192);
    int ch = tid & 63, wq = tid >> 6;
    float w0 = ldf(W1, 2 * ch, bf), w1v = ldf(W1, 2 * ch + 1, bf), bb1 = ldf(b1, ch, bf);
    const uint2* lut2 = (const uint2*)slut;
    for (int t = 0; t < 16; t++) {
        __syncthreads();   // t=0: staging done; t>0: prev MFMA done with xt
        {  // phase-B tile t (k2-v4 expressions verbatim; global rows t*64+...)
            u32 ow[8];
#pragma unroll
            for (int k2i = 0; k2i < 8; k2i++) {
                int lj = t * 64 + wq * 16 + 2 * k2i;
                float2 a0 = saxl[lj], a1 = saxl[lj + 1];
                float v0 = poolf[12544 + lj]     * fmaxf(fmaf(w0, a0.x, fmaf(w1v, a0.y, bb1)), 0.0f);
                float v1 = poolf[12544 + lj + 1] * fmaxf(fmaf(w0, a1.x, fmaf(w1v, a1.y, bb1)), 0.0f);
                ow[k2i] = (u32)f2bf(v0) | ((u32)f2bf(v1) << 16);
            }
            u32* xtd = (u32*)xt + ch * 36 + wq * 8;
            *(uint4*)xtd = make_uint4(ow[0], ow[1], ow[2], ow[3]);
            *(uint4*)(xtd + 4) = make_uint4(ow[4], ow[5], ow[6], ow[7]);
        }
        __syncthreads();   // xt ready
#pragma unroll
        for (int ks = 0; ks < 2; ks++) {
            short8_t bq[4];
#pragma unroll
            for (int rf = 0; rf < 4; rf++) {
                u32 mw = pool[(2 * t + ks) * 256 + w * 64 + rf * 16 + l15];
                u32 by = (mw >> (quad * 8)) & 0xFFu;
                bq[rf] = expand8(lut2, by);
            }
#pragma unroll
            for (int nb = 0; nb < 4; nb++) {
                short8_t af = *(const short8_t*)(xt + (nb * 16 + l15) * 72 + ks * 32 + quad * 8);
#pragma unroll
                for (int rf = 0; rf < 4; rf++)
                    acc[rf][nb] = __builtin_amdgcn_mfma_f32_16x16x32_bf16(af, bq[rf], acc[rf][nb], 0, 0, 0);
            }
        }
    }
    __syncthreads();

    // dump di*D^T as bf16 [256 rows][72 shorts] (overlays sbm)
    u32* dump = pool;
#pragma unroll
    for (int rf = 0; rf < 4; rf++) {
        int rn = w * 64 + rf * 16 + l15;
        float di = poolf[12544 + rowblk * 256 + rn];
#pragma unroll
        for (int nb = 0; nb < 4; nb++) {
            u32 lo = (u32)f2bf(acc[rf][nb][0] * di) | ((u32)f2bf(acc[rf][nb][1] * di) << 16);
            u32 hi = (u32)f2bf(acc[rf][nb][2] * di) | ((u32)f2bf(acc[rf][nb][3] * di) << 16);
            u32* dst = dump + rn * 36 + nb * 8 + quad * 2;
            dst[0] = lo; dst[1] = hi;
        }
    }
    __syncthreads();
    f32x4 xacc[4][4];  // [ob(o16-block)][rf]
#pragma unroll
    for (int ob = 0; ob < 4; ob++)
#pragma unroll
        for (int rf = 0; rf < 4; rf++)
#pragma unroll
            for (int r = 0; r < 4; r++) xacc[ob][rf][r] = 0.0f;
#pragma unroll
    for (int ks2 = 0; ks2 < 2; ks2++) {
        short8_t b2f[4];
#pragma unroll
        for (int rf = 0; rf < 4; rf++)
            b2f[rf] = *(const short8_t*)((const unsigned short*)dump +
                        (w * 64 + rf * 16 + l15) * 72 + ks2 * 32 + quad * 8);
#pragma unroll
        for (int ob = 0; ob < 4; ob++) {
            short8_t a2 = *(const short8_t*)(W2B + (ob * 16 + l15) * 72 + ks2 * 32 + quad * 8);
#pragma unroll
            for (int rf = 0; rf < 4; rf++)
                xacc[ob][rf] = __builtin_amdgcn_mfma_f32_16x16x32_bf16(a2, b2f[rf], xacc[ob][rf], 0, 0, 0);
        }
    }
#pragma unroll
    for (int ob = 0; ob < 4; ob++) {
#pragma unroll
        for (int r = 0; r < 4; r++) {
            int o = ob * 16 + quad * 4 + r;
            float bb = poolf[15872 + o];
            float s = 0.0f;
#pragma unroll
            for (int rf = 0; rf < 4; rf++) s += fmaxf(xacc[ob][rf][r] + bb, 0.0f);
            s += __shfl_down(s, 8, 16);
            s += __shfl_down(s, 4, 16);
            s += __shfl_down(s, 2, 16);
            s += __shfl_down(s, 1, 16);
            if (l15 == 0) atomicAdd(&gsum[bt * 64 + o], s);
        }
    }
}

// K4a: per-(b,t) precompute (parallel, 128 blocks x 384 thr, 1 blk/CU).
__global__ __launch_bounds__(384, 1) void k4a_gi(const void* __restrict__ pts,
                                                 const void* __restrict__ Wg,
                                                 const void* __restrict__ bg,
                                                 const void* __restrict__ Wih,
                                                 const void* __restrict__ bih,
                                                 const float* __restrict__ gsum,
                                                 float* __restrict__ gi_ws) {
    int blk = blockIdx.x, tid = threadIdx.x;   // blk = b*32 + t
    __shared__ float s_gm[64];
    __shared__ float s_x[64];
    __shared__ int s_flag;
    bool bf = detect_bf16(pts, tid, &s_flag);
    if (tid < 64) s_gm[tid] = gsum[(size_t)blk * 64 + tid] * (1.0f / 1024.0f);
    int r = tid;
    float wv[64];
    if (bf) {
#pragma unroll
        for (int k = 0; k < 64; k++) wv[k] = bfi(((const unsigned short*)Wih)[r * 64 + k]);
    } else {
        const float4* wr = (const float4*)Wih + r * 16;
#pragma unroll
        for (int qq = 0; qq < 16; qq++) {
            float4 v = wr[qq];
            wv[4*qq] = v.x; wv[4*qq+1] = v.y; wv[4*qq+2] = v.z; wv[4*qq+3] = v.w;
        }
    }
    float br = ldf(bih, r, bf);
    float wg[64];
    if (tid < 64) {                            // wave 0: Wg row c = tid
        if (bf) {
#pragma unroll
            for (int k = 0; k < 64; k++) wg[k] = bfi(((const unsigned short*)Wg)[tid * 64 + k]);
        } else {
            const float4* wr = (const float4*)Wg + tid * 16;
#pragma unroll
            for (int qq = 0; qq < 16; qq++) {
                float4 v = wr[qq];
                wg[4*qq] = v.x; wg[4*qq+1] = v.y; wg[4*qq+2] = v.z; wg[4*qq+3] = v.w;
            }
        }
    }
    __syncthreads();                           // s_gm ready
    if (tid < 64) {
        float gmv = s_gm[tid];                 // lane c holds gm[c]
        float s0 = ldf(bg, tid, bf), s1 = 0.f, s2 = 0.f, s3 = 0.f;
#pragma unroll
        for (int k = 0; k < 64; k += 4) {
            s0 = fmaf(wg[k],     rdlane(gmv, k),     s0);
            s1 = fmaf(wg[k + 1], rdlane(gmv, k + 1), s1);
            s2 = fmaf(wg[k + 2], rdlane(gmv, k + 2), s2);
            s3 = fmaf(wg[k + 3], rdlane(gmv, k + 3), s3);
        }
        s_x[tid] = (s0 + s1) + (s2 + s3);
    }
    __syncthreads();                           // s_x ready
    float xv = s_x[tid & 63];                  // lane k holds x[k]
    float s0 = br, s1 = 0.f, s2 = 0.f, s3 = 0.f;
#pragma unroll
    for (int k = 0; k < 64; k += 4) {
        s0 = fmaf(wv[k],     rdlane(xv, k),     s0);
        s1 = fmaf(wv[k + 1], rdlane(xv, k + 1), s1);
        s2 = fmaf(wv[k + 2], rdlane(xv, k + 2), s2);
        s3 = fmaf(wv[k + 3], rdlane(xv, k + 3), s3);
    }
    gi_ws[(size_t)blk * 384 + r] = (s0 + s1) + (s2 + s3);
}

// K4b v7: MFMA scan (R12, verified). gh = Whh@h via k2-pattern MFMA; Whh as
// hi/lo bf16 A-frags resident in VGPRs; h bf16 hi/lo in LDS; 3-term product.
__global__ __launch_bounds__(768, 1) void k4b_scan(const void* __restrict__ pts,
                                                   const void* __restrict__ Whh,
                                                   const void* __restrict__ bhh,
                                                   const void* __restrict__ Wf,
                                                   const void* __restrict__ bf_,
                                                   const float* __restrict__ gi_ws,
                                                   float* __restrict__ out) {
    int b = blockIdx.x, tid = threadIdx.x;
    __shared__ float s_gi[12288];      // 48 KB: [t][384]
    __shared__ float gh_lds[384];
    __shared__ unsigned short h_hi[128] __attribute__((aligned(16)));
    __shared__ unsigned short h_lo[128] __attribute__((aligned(16)));
    __shared__ float s_red[256];
    __shared__ int s_flag;
    bool bf = detect_bf16(pts, tid, &s_flag);
    const u32* gi_g = (const u32*)gi_ws + (size_t)b * 12288;
    u32* s_gi_u = (u32*)s_gi;
#pragma unroll
    for (int j = 0; j < 4; j++)
        gload16(gi_g + j * 3072 + tid * 4, s_gi_u + j * 3072 + tid * 4);

    int lane = tid & 63, w = tid >> 6;
    int l15 = lane & 15, quad = lane >> 4;
    short8_t whi[2][4], wlo[2][4];
#pragma unroll
    for (int tt = 0; tt < 2; tt++) {
        int row = (2 * w + tt) * 16 + l15;
#pragma unroll
        for (int s = 0; s < 4; s++) {
            union { uint4 u4; short8_t s8; } cv, cl;
            if (bf) {
                cv.u4 = *(const uint4*)((const unsigned short*)Whh + row * 128 + s * 32 + quad * 8);
                cl.u4 = make_uint4(0u, 0u, 0u, 0u);   // bf16 input: residual = 0
            } else {
                const float* wp = (const float*)Whh + row * 128 + s * 32 + quad * 8;
                float4 a = ((const float4*)wp)[0], b4 = ((const float4*)wp)[1];
                float v[8] = {a.x, a.y, a.z, a.w, b4.x, b4.y, b4.z, b4.w};
                unsigned short hh_[8], ll_[8];
#pragma unroll
                for (int i = 0; i < 8; i++) {
                    hh_[i] = f2bf(v[i]);
                    ll_[i] = f2bf(v[i] - bfi(hh_[i]));
                }
                cv.u4 = make_uint4((u32)hh_[0] | ((u32)hh_[1] << 16),
                                   (u32)hh_[2] | ((u32)hh_[3] << 16),
                                   (u32)hh_[4] | ((u32)hh_[5] << 16),
                                   (u32)hh_[6] | ((u32)hh_[7] << 16));
                cl.u4 = make_uint4((u32)ll_[0] | ((u32)ll_[1] << 16),
                                   (u32)ll_[2] | ((u32)ll_[3] << 16),
                                   (u32)ll_[4] | ((u32)ll_[5] << 16),
                                   (u32)ll_[6] | ((u32)ll_[7] << 16));
            }
            whi[tt][s] = cv.s8;
            wlo[tt][s] = cl.s8;
        }
    }
    float bhh_r = 0.f, bhh_z = 0.f, bhh_n = 0.f;
    if (tid < 128) {
        bhh_r = ldf(bhh, tid, bf);
        bhh_z = ldf(bhh, 128 + tid, bf);
        bhh_n = ldf(bhh, 256 + tid, bf);
        h_hi[tid] = 0; h_lo[tid] = 0;          // h0 = 0
    }
    float hval = 0.0f, hsum = 0.0f;
    __syncthreads();                           // drains gloads; h/frags ready

    for (int t = 0; t < 32; t++) {
        short8_t hh[4], hl[4];
#pragma unroll
        for (int s = 0; s < 4; s++) {
            hh[s] = *(const short8_t*)(h_hi + s * 32 + quad * 8);
            hl[s] = *(const short8_t*)(h_lo + s * 32 + quad * 8);
        }
        f32x4 acc0, acc1;
#pragma unroll
        for (int r = 0; r < 4; r++) { acc0[r] = 0.0f; acc1[r] = 0.0f; }
#pragma unroll
        for (int s = 0; s < 4; s++) {
            acc0 = __builtin_amdgcn_mfma_f32_16x16x32_bf16(wlo[0][s], hh[s], acc0, 0, 0, 0);
            acc0 = __builtin_amdgcn_mfma_f32_16x16x32_bf16(whi[0][s], hl[s], acc0, 0, 0, 0);
            acc0 = __builtin_amdgcn_mfma_f32_16x16x32_bf16(whi[0][s], hh[s], acc0, 0, 0, 0);
            acc1 = __builtin_amdgcn_mfma_f32_16x16x32_bf16(wlo[1][s], hh[s], acc1, 0, 0, 0);
            acc1 = __builtin_amdgcn_mfma_f32_16x16x32_bf16(whi[1][s], hl[s], acc1, 0, 0, 0);
            acc1 = __builtin_amdgcn_mfma_f32_16x16x32_bf16(whi[1][s], hh[s], acc1, 0, 0, 0);
        }
        if (l15 == 0) {                        // all 16 D-cols equal -> col 0
#pragma unroll
            for (int r = 0; r < 4; r++) {
                gh_lds[(2 * w) * 16 + quad * 4 + r]     = acc0[r];
                gh_lds[(2 * w + 1) * 16 + quad * 4 + r] = acc1[r];
            }
        }
        __syncthreads();                       // gh ready
        if (tid < 128) {
            int c = tid;
            float gi_r = s_gi[t * 384 + c];
            float gi_z = s_gi[t * 384 + 128 + c];
            float gi_n = s_gi[t * 384 + 256 + c];
            float gr = gi_r + (gh_lds[c] + bhh_r);
            float gz = gi_z + (gh_lds[128 + c] + bhh_z);
            float hn = gh_lds[256 + c] + bhh_n;
            float rr = sigm_f(gr);
            float z  = sigm_f(gz);
            float n  = tanh_f(fmaf(rr, hn, gi_n));
            hval = fmaf(z, hval - n, n);       // (1-z)*n + z*h
            hsum += hval;
            unsigned short hb = f2bf(hval);
            h_hi[c] = hb;
            h_lo[c] = f2bf(hval - bfi(hb));
        }
        __syncthreads();                       // h ready for next step
    }
    if (tid < 128) {
        float hm = hsum * (1.0f / 32.0f);
        s_red[tid]       = ldf(Wf, tid, bf) * hm;
        s_red[128 + tid] = ldf(Wf, 128 + tid, bf) * hm;
    }
    __syncthreads();
    if (tid < 2) {
        float s = ldf(bf_, tid, bf);
        for (int k = 0; k < 128; k++) s += s_red[tid * 128 + k];
        out[b * 2 + tid] = s;   // f32 output (verified R4)
    }
}

extern "C" void kernel_launch(void* const* d_in, const int* in_sizes, int n_in,
                              void* d_out, int out_size, void* d_ws, size_t ws_size,
                              hipStream_t stream) {
    const void* pts = d_in[0];
    const void* W1  = d_in[1];
    const void* b1  = d_in[2];
    const void* W2  = d_in[3];
    const void* b2  = d_in[4];
    const void* Wg  = d_in[5];
    const void* bg  = d_in[6];
    const void* Wih = d_in[7];
    const void* Whh = d_in[8];
    const void* bih = d_in[9];
    const void* bhh = d_in[10];
    const void* Wf  = d_in[11];
    const void* bf_ = d_in[12];

    // ws: dinv 512K | gsum 32K | bm 16M | sax 1M | gi 192K  (~17.8 MB)
    float* dinv  = (float*)d_ws;
    float* gsum  = dinv + (size_t)BT * N_PTS;
    u32*   bm    = (u32*)(gsum + BT * 64);
    float* sax_g = (float*)(bm + (size_t)BT * 32768);
    float* gi_ws = sax_g + (size_t)BT * 2048;

    k1_bm  <<<512, 256, 0, stream>>>(pts, dinv, gsum, bm);
    k2_sax <<<512, 256, 0, stream>>>(pts, dinv, bm, sax_g);
    k3_mfma<<<512, 256, 0, stream>>>(pts, W1, b1, W2, b2, dinv, bm, sax_g, gsum);
    k4a_gi <<<128, 384, 0, stream>>>(pts, Wg, bg, Wih, bih, gsum, gi_ws);
    k4b_scan<<<4, 768, 0, stream>>>(pts, Whh, bhh, Wf, bf_, gi_ws, (float*)d_out);
}